// Round 5
// baseline (354.245 us; speedup 1.0000x reference)
//
#include <hip/hip_runtime.h>
#include <stdint.h>

typedef __attribute__((ext_vector_type(8))) short bf16x8_t;   // 8 bf16 in 4 VGPRs
typedef __attribute__((ext_vector_type(4))) float f32x4_t;

#define DI __device__ __forceinline__
#define SBAR() asm volatile("s_barrier" ::: "memory")
#define VMW(n) asm volatile("s_waitcnt vmcnt(" #n ")" ::: "memory")

DI unsigned short f2b(float f) {
  union { float f; unsigned int u; } c; c.f = f;
  unsigned int u = c.u + 0x7FFFu + ((c.u >> 16) & 1u);   // RNE
  return (unsigned short)(u >> 16);
}
DI unsigned int pack2(float lo, float hi) {
  return (unsigned int)f2b(lo) | ((unsigned int)f2b(hi) << 16);
}
DI float b2f(unsigned short h) {
  union { unsigned int u; float f; } c; c.u = ((unsigned int)h) << 16;
  return c.f;
}
DI float silu_f(float z) { return z / (1.0f + __expf(-z)); }

// async global->LDS, 16B per lane; LDS dst = wave-uniform base + lane*16B
DI void load_lds16(const unsigned short* g, unsigned short* l) {
  __builtin_amdgcn_global_load_lds(
      (const __attribute__((address_space(1))) unsigned int*)g,
      (__attribute__((address_space(3))) unsigned int*)l,
      16, 0, 0);
}

// ---------------------------------------------------------------- prep mega-kernel
struct PrepP {
  const float *Wh, *Wo, *Wqk, *x, *g, *b;
  unsigned short *WT, *WoT, *normed;
  unsigned int* flag;
};

__global__ __launch_bounds__(256) void prep_kernel(PrepP p) {
  const int blk = blockIdx.x;
  if (blk >= 14464) {                 // R8: zero the qk-done flag every iteration
    if (threadIdx.x == 0) *p.flag = 0u;
    return;
  }
  const int tx = threadIdx.x & 31, ty = threadIdx.x >> 5;
  if (blk < 6272) {
    const float* in; unsigned short* out; int R, C, gx;
    if (blk < 4096)      { in = p.Wh;  out = p.WT;                 R = 1024; C = 4096; gx = blk; }
    else if (blk < 6144) { in = p.Wo;  out = p.WoT;                R = 2048; C = 1024; gx = blk - 4096; }
    else                 { in = p.Wqk; out = p.WT + 4096 * 1024;   R = 1024; C = 128;  gx = blk - 6144; }
    const int xTiles = C >> 5;
    const int c0 = (gx % xTiles) * 32, r0 = (gx / xTiles) * 32;
    __shared__ float tile[32][33];
#pragma unroll
    for (int i = 0; i < 4; ++i)
      tile[ty + 8 * i][tx] = in[(long)(r0 + ty + 8 * i) * C + c0 + tx];
    __syncthreads();
#pragma unroll
    for (int i = 0; i < 4; ++i)
      out[(long)(c0 + ty + 8 * i) * R + r0 + tx] = f2b(tile[tx][ty + 8 * i]);
  } else {
    const int row = blk - 6272, tid = threadIdx.x;
    __shared__ float red[8];
    float4 v = ((const float4*)(p.x + (long)row * 1024))[tid];
    float s = v.x + v.y + v.z + v.w;
    float ss = v.x * v.x + v.y * v.y + v.z * v.z + v.w * v.w;
    for (int o = 32; o > 0; o >>= 1) { s += __shfl_down(s, o); ss += __shfl_down(ss, o); }
    const int wave = tid >> 6, lane = tid & 63;
    if (lane == 0) { red[wave * 2] = s; red[wave * 2 + 1] = ss; }
    __syncthreads();
    if (tid == 0) {
      float S = red[0] + red[2] + red[4] + red[6];
      float SS = red[1] + red[3] + red[5] + red[7];
      float mu = S * (1.0f / 1024.0f);
      float var = SS * (1.0f / 1024.0f) - mu * mu;
      red[0] = mu; red[1] = rsqrtf(var + 1e-5f);
    }
    __syncthreads();
    const float mu = red[0], rstd = red[1];
    float4 gg = ((const float4*)p.g)[tid];
    float4 bb = ((const float4*)p.b)[tid];
    ushort4 o;
    o.x = f2b((v.x - mu) * rstd * gg.x + bb.x);
    o.y = f2b((v.y - mu) * rstd * gg.y + bb.y);
    o.z = f2b((v.z - mu) * rstd * gg.z + bb.z);
    o.w = f2b((v.w - mu) * rstd * gg.w + bb.w);
    ((ushort4*)(p.normed + (long)row * 1024))[tid] = o;
  }
}

// ---------------------------------------------------------------- reduce 8 bf16 slabs -> bf16
__global__ __launch_bounds__(256) void reduce_cvt(
    const unsigned short* __restrict__ part, unsigned short* __restrict__ out) {
  const int idx = blockIdx.x * 256 + threadIdx.x;
  const int b = idx >> 16, i = idx & 65535;
  float4 s = make_float4(0.f, 0.f, 0.f, 0.f);
#pragma unroll
  for (int sl = 0; sl < 8; ++sl) {
    ushort4 v = ((const ushort4*)part)[(long)(b * 8 + sl) * 65536 + i];
    s.x += b2f(v.x); s.y += b2f(v.y); s.z += b2f(v.z); s.w += b2f(v.w);
  }
  ushort4 o;
  o.x = f2b(s.x); o.y = f2b(s.y); o.z = f2b(s.z); o.w = f2b(s.w);
  ((ushort4*)out)[(long)b * 65536 + i] = o;
}

// ---------------------------------------------------------------- 8-wave 256^2 deep-pipelined GEMM1
// R8: grid 672. Blocks 0..31 qk (release device flag when stored); 32..543
// v/gate (XCD-chunk swizzled); 544..671 = FUSED ARELU (attn = relu^2(qq@qkh/256))
// riding the otherwise-wasted 3rd dispatch pass (1 block/CU at 128KB LDS =>
// 544 blocks = 2.125 passes; pass 3 had 224 idle CUs). ARELU blocks spin-
// acquire the flag (<=128 spinners < 256 CU slots => no deadlock; G16-safe).
struct G8P {
  const unsigned short* A;
  const unsigned short* B;
  const float* bias;          // b_hidden[4096]
  const float* bias2;         // b_qk[128]
  const float* gamma;         // os_gamma [4][128]
  const float* beta;          // os_beta  [4][128]
  unsigned short* vTout;      // [4][2048 e][2048 n]
  unsigned short* gateOut;    // [8192][2048]
  unsigned short* qqO;        // [8192][128]
  unsigned short* lqO;
  unsigned short* qkhO;
  unsigned short* lkTO;       // [4][128][2048]
  unsigned short* attnO;      // [32][256][256]
  unsigned int* flag;
};

__global__ __launch_bounds__(512, 2) void gemm8p(G8P p) {
  extern __shared__ unsigned char lds[];   // 131072 B dynamic
  const int tid  = threadIdx.x;
  const int lane = tid & 63;
  const int wave = tid >> 6;
  const int lm = lane & 15;
  const int kb = lane >> 4;
  const int fxor = (kb << 4) ^ (((lm >> 1) & 3) << 4);

  // ---------------- fused ARELU blocks (tail pass) ----------------
  if (blockIdx.x >= 544) {
    const int az = blockIdx.x - 544;          // 0..127
    const int zz = az >> 2;                   // 0..31 (b*8+g)
    const int bq = (az >> 1) & 1, bn = az & 1;
    // acquire: wait for all 32 qk blocks
    if (tid == 0) {
      while (atomicAdd(p.flag, 0u) < 32u) __builtin_amdgcn_s_sleep(2);
    }
    __syncthreads();
    __threadfence();
    // stage all 4 K-tiles of A(qq half) and B(qkh half): 64KB, same swizzle
    const int r128 = tid >> 2;
    const int kby2 = ((tid & 3) << 4) ^ (((r128 >> 1) & 3) << 4);
    const unsigned short* gq = p.qqO  + ((long)zz * 256 + bq * 128 + r128) * 128 + (kby2 >> 1);
    const unsigned short* gk = p.qkhO + ((long)zz * 256 + bn * 128 + r128) * 128 + (kby2 >> 1);
#pragma unroll
    for (int kt = 0; kt < 4; ++kt) {
      load_lds16(gq + kt * 32, (unsigned short*)(lds + kt * 8192 + wave * 1024));
      load_lds16(gk + kt * 32, (unsigned short*)(lds + 32768 + kt * 8192 + wave * 1024));
    }
    VMW(0);
    __syncthreads();
    const int wm2 = (wave & 1) * 64;
    const int wn2 = (wave >> 1) * 32;
    f32x4_t ac[4][2];
#pragma unroll
    for (int i = 0; i < 4; ++i)
#pragma unroll
      for (int j = 0; j < 2; ++j) ac[i][j] = (f32x4_t){0.f, 0.f, 0.f, 0.f};
#pragma unroll
    for (int kt = 0; kt < 4; ++kt) {
      bf16x8_t aF2[4], bF2[2];
#pragma unroll
      for (int i = 0; i < 4; ++i)
        aF2[i] = *(const bf16x8_t*)(lds + kt * 8192 + (wm2 + i * 16 + lm) * 64 + fxor);
#pragma unroll
      for (int j = 0; j < 2; ++j)
        bF2[j] = *(const bf16x8_t*)(lds + 32768 + kt * 8192 + (wn2 + j * 16 + lm) * 64 + fxor);
#pragma unroll
      for (int i = 0; i < 4; ++i)
#pragma unroll
        for (int j = 0; j < 2; ++j)
          ac[i][j] = __builtin_amdgcn_mfma_f32_16x16x32_bf16(aF2[i], bF2[j], ac[i][j], 0, 0, 0);
    }
    unsigned short* outA = p.attnO + (long)zz * 65536;
#pragma unroll
    for (int i = 0; i < 4; ++i) {
      const int row0 = bq * 128 + wm2 + i * 16 + (lane >> 4) * 4;
#pragma unroll
      for (int j = 0; j < 2; ++j) {
        const int col = bn * 128 + wn2 + j * 16 + lm;
#pragma unroll
        for (int r = 0; r < 4; ++r) {
          float s = ac[i][j][r] * (1.0f / 256.0f);
          s = s > 0.f ? s : 0.f;
          outA[(row0 + r) * 256 + col] = f2b(s * s);
        }
      }
    }
    return;
  }

  // ---------------- main GEMM blocks ----------------
  const bool qk = blockIdx.x < 32;
  int bx, by;
  if (qk) { bx = blockIdx.x; by = 16; }                // B rows 4096..
  else {
    const int vg = blockIdx.x - 32;                    // 0..511
    const int vgs = (vg & 7) * 64 + (vg >> 3);         // XCD-chunk swizzle (bijective)
    bx = vgs >> 4; by = vgs & 15;
  }
  const int wm = (wave & 1) * 128;
  const int wn = (wave >> 1) * 64;

  // ---- staging coords (pre-swizzled global source; LDS lands linear) ----
  const int rA  = tid >> 2;                                    // 0..127
  const int kby = ((tid & 3) << 4) ^ (((rA >> 1) & 3) << 4);   // 2-way swizzle
  const unsigned short* gA0 = p.A + (long)(bx * 256 + rA) * 1024 + (kby >> 1);
  const unsigned short* gA1 = gA0 + 128 * 1024;
  const unsigned short* gB0 = p.B + (long)(by * 256 + rA) * 1024 + (kby >> 1);
  const unsigned short* gB1 = gB0 + 128 * 1024;

  f32x4_t acc[8][4];
#pragma unroll
  for (int i = 0; i < 8; ++i)
#pragma unroll
    for (int j = 0; j < 4; ++j) acc[i][j] = (f32x4_t){0.f, 0.f, 0.f, 0.f};

  auto stageA = [&](int t) {
    unsigned short* l = (unsigned short*)(lds + (t & 3) * 32768 + wave * 1024);
    load_lds16(gA0 + t * 32, l);
    load_lds16(gA1 + t * 32, (unsigned short*)((unsigned char*)l + 8192));
  };
  auto stageB = [&](int t) {
    unsigned short* l = (unsigned short*)(lds + (t & 3) * 32768 + 16384 + wave * 1024);
    load_lds16(gB0 + t * 32, l);
    load_lds16(gB1 + t * 32, (unsigned short*)((unsigned char*)l + 8192));
  };

  // prologue: 3 tiles in flight (12 loads/thread)
#pragma unroll
  for (int u = 0; u < 3; ++u) { stageA(u); stageB(u); }
  VMW(8);
  SBAR();

  constexpr int NT = 16;
#pragma unroll 1
  for (int t = 0; t < NT; ++t) {
    const unsigned char* slot = lds + (t & 3) * 32768;
    bf16x8_t bF[4], aF[4];
#pragma unroll
    for (int j = 0; j < 4; ++j)
      bF[j] = *(const bf16x8_t*)(slot + 16384 + (wn + j * 16 + lm) * 64 + fxor);
#pragma unroll
    for (int i = 0; i < 4; ++i)
      aF[i] = *(const bf16x8_t*)(slot + (wm + i * 16 + lm) * 64 + fxor);
    if (t <= NT - 4) stageA(t + 3);
    SBAR();
    __builtin_amdgcn_s_setprio(1);
#pragma unroll
    for (int i = 0; i < 4; ++i)
#pragma unroll
      for (int j = 0; j < 4; ++j)
        acc[i][j] = __builtin_amdgcn_mfma_f32_16x16x32_bf16(aF[i], bF[j], acc[i][j], 0, 0, 0);
    __builtin_amdgcn_s_setprio(0);
    SBAR();
#pragma unroll
    for (int i = 0; i < 4; ++i)
      aF[i] = *(const bf16x8_t*)(slot + (wm + 64 + i * 16 + lm) * 64 + fxor);
    if (t <= NT - 4) stageB(t + 3);
    SBAR();
    __builtin_amdgcn_s_setprio(1);
#pragma unroll
    for (int i = 0; i < 4; ++i)
#pragma unroll
      for (int j = 0; j < 4; ++j)
        acc[i + 4][j] = __builtin_amdgcn_mfma_f32_16x16x32_bf16(aF[i], bF[j], acc[i + 4][j], 0, 0, 0);
    __builtin_amdgcn_s_setprio(0);
    if (t <= NT - 4)      { VMW(8); }
    else if (t == NT - 3) { VMW(4); }
    else if (t == NT - 2) { VMW(0); }
    SBAR();
  }

  // ---------------- epilogue ----------------
  if (qk) {
    // silu -> LDS [256][136] -> OffsetScale+RoPE. Waves 0..3 hold cols 0..127.
    unsigned short* q16 = (unsigned short*)lds;
    if (wave < 4) {
#pragma unroll
      for (int i = 0; i < 8; ++i) {
        const int rloc = wm + i * 16 + (lane >> 4) * 4;   // 0..255
#pragma unroll
        for (int j = 0; j < 4; ++j) {
          const int cl = wn + j * 16 + lm;                // 0..127
          const float bb = p.bias2[cl];
#pragma unroll
          for (int r = 0; r < 4; ++r)
            q16[(rloc + r) * 136 + cl] = f2b(silu_f(acc[i][j][r] + bb));
        }
      }
    }
    __syncthreads();
    const int j = tid & 63;
    const int rq = tid >> 6;                              // 0..7
    const float freq = powf(10000.0f, (float)j * (1.0f / 64.0f));
    float ga[4], gb[4], ea[4], eb[4];
#pragma unroll
    for (int h = 0; h < 4; ++h) {
      ga[h] = p.gamma[h * 128 + j];  gb[h] = p.gamma[h * 128 + 64 + j];
      ea[h] = p.beta[h * 128 + j];   eb[h] = p.beta[h * 128 + 64 + j];
    }
    unsigned short* outs[3] = {p.qqO, p.lqO, p.qkhO};
    for (int rr = 0; rr < 32; ++rr) {
      const int row = rr * 8 + rq;                        // 0..255
      const float x1 = b2f(q16[row * 136 + j]);
      const float x2 = b2f(q16[row * 136 + 64 + j]);
      const int tok = bx * 256 + row;
      const int pos = tok & 2047, bidx = tok >> 11;
      const float ang = (float)pos * freq;
      const float sn = sinf(ang), cs = cosf(ang);
#pragma unroll
      for (int h = 0; h < 3; ++h) {
        const float y1 = x1 * ga[h] + ea[h], y2 = x2 * gb[h] + eb[h];
        outs[h][(long)tok * 128 + j] = f2b(y1 * cs - y2 * sn);
        outs[h][(long)tok * 128 + 64 + j] = f2b(y2 * cs + y1 * sn);
      }
      const float y1 = x1 * ga[3] + ea[3], y2 = x2 * gb[3] + eb[3];
      p.lkTO[((long)bidx * 128 + j) * 2048 + pos] = f2b(y1 * cs - y2 * sn);
      p.lkTO[((long)bidx * 128 + 64 + j) * 2048 + pos] = f2b(y2 * cs + y1 * sn);
    }
    // release: qq/qkh visible, then count this block
    __threadfence();
    __syncthreads();
    if (tid == 0) atomicAdd(p.flag, 1u);
  } else if (by < 8) {
    // v half: silu+bias, pack pairs, full 256x256 transpose via 128KB LDS,
    // coalesced 512B vT row stores. Chunk-XOR (e&7) kills transpose conflicts.
    unsigned int* Cx = (unsigned int*)lds;
#pragma unroll
    for (int i = 0; i < 8; ++i) {
      const int c0 = (wm + i * 16) / 2 + (lane >> 4) * 2;   // even uint col
#pragma unroll
      for (int j = 0; j < 4; ++j) {
        const int e = wn + j * 16 + lm;
        const float bb = p.bias[by * 256 + e];
        const float s0 = silu_f(acc[i][j][0] + bb);
        const float s1 = silu_f(acc[i][j][1] + bb);
        const float s2 = silu_f(acc[i][j][2] + bb);
        const float s3 = silu_f(acc[i][j][3] + bb);
        const int x = (e & 7) << 2;
        Cx[e * 128 + (c0 ^ x)]     = pack2(s0, s1);
        Cx[e * 128 + (c0 ^ x) + 1] = pack2(s2, s3);
      }
    }
    __syncthreads();
    const int bq = bx >> 3, nloc0 = (bx & 7) * 256, e0g = by * 256;
    unsigned short* dstBase = p.vTout + ((long)(bq * 2048 + e0g)) * 2048 + nloc0;
#pragma unroll
    for (int rep = 0; rep < 16; ++rep) {
      const int flat = rep * 512 + tid;
      const int e = flat >> 5, q = flat & 31;
      uint4 val = *(const uint4*)(Cx + e * 128 + ((q ^ (e & 7)) << 2));
      *(uint4*)(dstBase + (long)e * 2048 + q * 8) = val;
    }
  } else {
    // gate half
#pragma unroll
    for (int i = 0; i < 8; ++i) {
      const int row0 = bx * 256 + wm + i * 16 + (lane >> 4) * 4;
#pragma unroll
      for (int j = 0; j < 4; ++j) {
        const int colg = by * 256 + wn + j * 16 + lm;   // 2048..4095
        const float bb = p.bias[colg];
#pragma unroll
        for (int r = 0; r < 4; ++r)
          p.gateOut[(long)(row0 + r) * 2048 + colg - 2048] =
              f2b(silu_f(acc[i][j][r] + bb));
      }
    }
  }
}

// ---------------------------------------------------------------- QUADLIN: A3 = gate*(attn@vg + lq@lkv)
struct GQLP {
  const unsigned short* attn;   // [32][256][256]
  const unsigned short* vT;     // [4][2048][2048]
  const unsigned short* lq;     // [8192][128]
  const unsigned short* lkvT;   // [4][2048][128]
  const unsigned short* gateIn; // [8192][2048]
  unsigned short* outU;         // A3 [8192][2048]
};

__global__ __launch_bounds__(512, 2) void gemmQL(GQLP p) {
  extern __shared__ unsigned char lds[];   // 131072 B dynamic
  const int tid  = threadIdx.x;
  const int lane = tid & 63;
  const int wave = tid >> 6;
  const int sb = (blockIdx.x & 7) * 32 + (blockIdx.x >> 3);   // XCD-chunk swizzle
  const int z  = sb >> 3;            // 0..31 (b*8+g)
  const int by = sb & 7;             // 0..7  (n-tile of 2048)
  const int b = z >> 3, g = z & 7;
  const int wm = (wave & 1) * 128;
  const int wn = (wave >> 1) * 64;
  const int lm = lane & 15;
  const int kb = lane >> 4;

  const int rA  = tid >> 2;                                    // 0..127
  const int kby = ((tid & 3) << 4) ^ (((rA >> 1) & 3) << 4);
  const int swz = kby >> 1;                                    // shorts
  const unsigned short* a1 = p.attn + (long)z * 65536 + rA * 256 + swz;
  const unsigned short* a2 = p.lq + ((long)z * 256 + rA) * 128 + swz;
  const unsigned short* b1 = p.vT + (long)b * 4194304 + (long)(by * 256 + rA) * 2048 + g * 256 + swz;
  const unsigned short* b2 = p.lkvT + (long)b * 262144 + (by * 256 + rA) * 128 + swz;
  const int fxor = (kb << 4) ^ (((lm >> 1) & 3) << 4);

  f32x4_t acc[8][4];
#pragma unroll
  for (int i = 0; i < 8; ++i)
#pragma unroll
    for (int j = 0; j < 4; ++j) acc[i][j] = (f32x4_t){0.f, 0.f, 0.f, 0.f};

  auto stageA = [&](int tt) {
    unsigned short* l  = (unsigned short*)(lds + (tt & 3) * 32768 + wave * 1024);
    unsigned short* lh = (unsigned short*)(lds + (tt & 3) * 32768 + wave * 1024 + 8192);
    if (tt < 8) { load_lds16(a1 + tt * 32, l); load_lds16(a1 + 128 * 256 + tt * 32, lh); }
    else { const int k2 = (tt - 8) * 32;
           load_lds16(a2 + k2, l); load_lds16(a2 + 128 * 128 + k2, lh); }
  };
  auto stageB = [&](int tt) {
    unsigned short* l  = (unsigned short*)(lds + (tt & 3) * 32768 + 16384 + wave * 1024);
    unsigned short* lh = (unsigned short*)(lds + (tt & 3) * 32768 + 16384 + wave * 1024 + 8192);
    if (tt < 8) { load_lds16(b1 + tt * 32, l); load_lds16(b1 + 128 * 2048 + tt * 32, lh); }
    else { const int k2 = (tt - 8) * 32;
           load_lds16(b2 + k2, l); load_lds16(b2 + 128 * 128 + k2, lh); }
  };

#pragma unroll
  for (int u = 0; u < 3; ++u) { stageA(u); stageB(u); }
  VMW(8);
  SBAR();

  constexpr int NT = 12;   // 8 (K=256 phase1) + 4 (K=128 phase2)
#pragma unroll 1
  for (int t = 0; t < NT; ++t) {
    const unsigned char* slot = lds + (t & 3) * 32768;
    bf16x8_t bF[4], aF[4];
#pragma unroll
    for (int j = 0; j < 4; ++j)
      bF[j] = *(const bf16x8_t*)(slot + 16384 + (wn + j * 16 + lm) * 64 + fxor);
#pragma unroll
    for (int i = 0; i < 4; ++i)
      aF[i] = *(const bf16x8_t*)(slot + (wm + i * 16 + lm) * 64 + fxor);
    if (t <= NT - 4) stageA(t + 3);
    SBAR();
    __builtin_amdgcn_s_setprio(1);
#pragma unroll
    for (int i = 0; i < 4; ++i)
#pragma unroll
      for (int j = 0; j < 4; ++j)
        acc[i][j] = __builtin_amdgcn_mfma_f32_16x16x32_bf16(aF[i], bF[j], acc[i][j], 0, 0, 0);
    __builtin_amdgcn_s_setprio(0);
    SBAR();
#pragma unroll
    for (int i = 0; i < 4; ++i)
      aF[i] = *(const bf16x8_t*)(slot + (wm + 64 + i * 16 + lm) * 64 + fxor);
    if (t <= NT - 4) stageB(t + 3);
    SBAR();
    __builtin_amdgcn_s_setprio(1);
#pragma unroll
    for (int i = 0; i < 4; ++i)
#pragma unroll
      for (int j = 0; j < 4; ++j)
        acc[i + 4][j] = __builtin_amdgcn_mfma_f32_16x16x32_bf16(aF[i], bF[j], acc[i + 4][j], 0, 0, 0);
    __builtin_amdgcn_s_setprio(0);
    if (t <= NT - 4)      { VMW(8); }
    else if (t == NT - 3) { VMW(4); }
    else if (t == NT - 2) { VMW(0); }
    SBAR();
  }

  // epilogue: A3 = gate * acc
#pragma unroll
  for (int i = 0; i < 8; ++i) {
    const int row0 = z * 256 + wm + i * 16 + (lane >> 4) * 4;
#pragma unroll
    for (int j = 0; j < 4; ++j) {
      const int col = by * 256 + wn + j * 16 + lm;
#pragma unroll
      for (int r = 0; r < 4; ++r) {
        const long idx = (long)(row0 + r) * 2048 + col;
        p.outU[idx] = f2b(b2f(p.gateIn[idx]) * acc[i][j][r]);
      }
    }
  }
}

// ---------------------------------------------------------------- FINAL: A3 @ WoT + b_out + x
struct GWoP {
  const unsigned short* A;   // A3 [8192][2048]
  const unsigned short* B;   // WoT [1024][2048]
  const float* bias;         // b_out[1024]
  const float* xres;         // x fp32 [8192][1024]
  float* outF;               // [8192][1024]
};

__global__ __launch_bounds__(512, 2) void gemmWo(GWoP p) {
  extern __shared__ unsigned char lds[];   // 4 * 24576 = 98304 B dynamic
  const int tid  = threadIdx.x;
  const int lane = tid & 63;
  const int wave = tid >> 6;
  const int sb = (blockIdx.x & 7) * 32 + (blockIdx.x >> 3);   // XCD-chunk swizzle
  const int bx = sb >> 3;                  // 0..31 (m-tile, 256 rows)
  const int by = sb & 7;                   // 0..7  (n-tile, 128 cols)
  const int wm = (wave & 1) * 128;
  const int wn = (wave >> 1) * 32;         // 4 n-groups of 32
  const int lm = lane & 15;
  const int kb = lane >> 4;

  const int rA  = tid >> 2;                                    // 0..127
  const int kby = ((tid & 3) << 4) ^ (((rA >> 1) & 3) << 4);
  const unsigned short* gA0 = p.A + (long)(bx * 256 + rA) * 2048 + (kby >> 1);
  const unsigned short* gA1 = gA0 + 128 * 2048;
  const unsigned short* gB0 = p.B + (long)(by * 128 + rA) * 2048 + (kby >> 1);
  const int fxor = (kb << 4) ^ (((lm >> 1) & 3) << 4);

  f32x4_t acc[8][2];
#pragma unroll
  for (int i = 0; i < 8; ++i)
#pragma unroll
    for (int j = 0; j < 2; ++j) acc[i][j] = (f32x4_t){0.f, 0.f, 0.f, 0.f};

  auto stageA = [&](int t) {
    unsigned short* l = (unsigned short*)(lds + (t & 3) * 24576 + wave * 1024);
    load_lds16(gA0 + t * 32, l);
    load_lds16(gA1 + t * 32, (unsigned short*)((unsigned char*)l + 8192));
  };
  auto stageB = [&](int t) {   // 128 rows x 64B = 8KB = 1 load/thread
    unsigned short* l = (unsigned short*)(lds + (t & 3) * 24576 + 16384 + wave * 1024);
    load_lds16(gB0 + t * 32, l);
  };

#pragma unroll
  for (int u = 0; u < 3; ++u) { stageA(u); stageB(u); }   // 9 in flight
  VMW(6);
  SBAR();

  constexpr int NT = 64;   // K=2048 / BK=32
#pragma unroll 1
  for (int t = 0; t < NT; ++t) {
    const unsigned char* slot = lds + (t & 3) * 24576;
    bf16x8_t bF[2], aF[4];
#pragma unroll
    for (int j = 0; j < 2; ++j)
      bF[j] = *(const bf16x8_t*)(slot + 16384 + (wn + j * 16 + lm) * 64 + fxor);
#pragma unroll
    for (int i = 0; i < 4; ++i)
      aF[i] = *(const bf16x8_t*)(slot + (wm + i * 16 + lm) * 64 + fxor);
    if (t <= NT - 4) stageA(t + 3);
    SBAR();
    __builtin_amdgcn_s_setprio(1);
#pragma unroll
    for (int i = 0; i < 4; ++i)
#pragma unroll
      for (int j = 0; j < 2; ++j)
        acc[i][j] = __builtin_amdgcn_mfma_f32_16x16x32_bf16(aF[i], bF[j], acc[i][j], 0, 0, 0);
    __builtin_amdgcn_s_setprio(0);
    SBAR();
#pragma unroll
    for (int i = 0; i < 4; ++i)
      aF[i] = *(const bf16x8_t*)(slot + (wm + 64 + i * 16 + lm) * 64 + fxor);
    if (t <= NT - 4) stageB(t + 3);
    SBAR();
    __builtin_amdgcn_s_setprio(1);
#pragma unroll
    for (int i = 0; i < 4; ++i)
#pragma unroll
      for (int j = 0; j < 2; ++j)
        acc[i + 4][j] = __builtin_amdgcn_mfma_f32_16x16x32_bf16(aF[i], bF[j], acc[i + 4][j], 0, 0, 0);
    __builtin_amdgcn_s_setprio(0);
    if (t <= NT - 4)      { VMW(6); }
    else if (t == NT - 3) { VMW(3); }
    else if (t == NT - 2) { VMW(0); }
    SBAR();
  }

  // epilogue: + bias + x residual, fp32 out
#pragma unroll
  for (int i = 0; i < 8; ++i) {
    const int row0 = bx * 256 + wm + i * 16 + (lane >> 4) * 4;
#pragma unroll
    for (int j = 0; j < 2; ++j) {
      const int col = by * 128 + wn + j * 16 + lm;
      const float bb = p.bias[col];
#pragma unroll
      for (int r = 0; r < 4; ++r) {
        const long idx = (long)(row0 + r) * 1024 + col;
        p.outF[idx] = acc[i][j][r] + bb + p.xres[idx];
      }
    }
  }
}

// ---------------------------------------------------------------- GEMM (BT) 128^2 (PART only)
struct GemmP {
  const unsigned short* A;
  const unsigned short* B;
  int K, lda, ldb, ldc;
  long aZ, bZ;
  float scale;
  unsigned short* outU;
};

__global__ __launch_bounds__(256, 2) void gemm_part(GemmP p) {
  __shared__ __align__(16) unsigned char smem[16384];
  unsigned short* As = (unsigned short*)smem;             // [128][32] bf16
  unsigned short* Bs = (unsigned short*)(smem + 8192);    // [128][32] bf16

  const int tid = threadIdx.x;
  const int lane = tid & 63;
  const int wave = tid >> 6;
  const int bx = blockIdx.x;
  const int by = blockIdx.y;
  const int z = blockIdx.z;

  unsigned short* lA = As + wave * 32 * 32;
  unsigned short* lB = Bs + wave * 32 * 32;
  const int wm = (wave & 1) * 64;
  const int wn = (wave >> 1) * 64;
  const int lm = lane & 15;
  const int kb = lane >> 4;
  const int rowSel = (wave * 32 + (lane >> 2));   // staging row within 128-tile
  const int colSel = (lane & 3) * 8;              // staging k-offset

  f32x4_t acc[4][4];
#pragma unroll
  for (int i = 0; i < 4; ++i)
#pragma unroll
    for (int j = 0; j < 4; ++j) acc[i][j] = (f32x4_t){0.f, 0.f, 0.f, 0.f};

  const int b = z >> 3, s = z & 7;   // split-K: 8 slices of 256
  const unsigned short* Ag = p.A + (long)b * p.aZ + s * 256 + (long)(bx * 128 + rowSel) * p.lda + colSel;
  const unsigned short* Bg = p.B + (long)b * p.bZ + s * 256 + (long)(by * 128 + rowSel) * p.ldb + colSel;
  const int a16 = 16 * p.lda, b16 = 16 * p.ldb;
  for (int kt = 0; kt < (p.K >> 5); ++kt) {
    load_lds16(Ag, lA);
    load_lds16(Ag + a16, lA + 512);
    load_lds16(Bg, lB);
    load_lds16(Bg + b16, lB + 512);
    Ag += 32; Bg += 32;
    __syncthreads();
    bf16x8_t aF[4], bF[4];
#pragma unroll
    for (int i = 0; i < 4; ++i)
      aF[i] = *(const bf16x8_t*)(As + (wm + i * 16 + lm) * 32 + kb * 8);
#pragma unroll
    for (int j = 0; j < 4; ++j)
      bF[j] = *(const bf16x8_t*)(Bs + (wn + j * 16 + lm) * 32 + kb * 8);
#pragma unroll
    for (int i = 0; i < 4; ++i)
#pragma unroll
      for (int j = 0; j < 4; ++j)
        acc[i][j] = __builtin_amdgcn_mfma_f32_16x16x32_bf16(aF[i], bF[j], acc[i][j], 0, 0, 0);
    __syncthreads();
  }

#pragma unroll
  for (int i = 0; i < 4; ++i) {
    const int row0 = bx * 128 + wm + i * 16 + (lane >> 4) * 4;
#pragma unroll
    for (int j = 0; j < 4; ++j) {
      const int col = by * 128 + wn + j * 16 + lm;
      unsigned short* slab = p.outU + (long)z * 262144;  // z = b*8+s
#pragma unroll
      for (int r = 0; r < 4; ++r)
        slab[(row0 + r) * (long)p.ldc + col] = f2b(acc[i][j][r] * p.scale);
    }
  }
}

// ---------------------------------------------------------------- launch
extern "C" void kernel_launch(void* const* d_in, const int* in_sizes, int n_in,
                              void* d_out, int out_size, void* d_ws, size_t ws_size,
                              hipStream_t stream) {
  const float* x        = (const float*)d_in[0];
  const float* ln_g     = (const float*)d_in[1];
  const float* ln_b     = (const float*)d_in[2];
  const float* W_hidden = (const float*)d_in[3];
  const float* b_hidden = (const float*)d_in[4];
  const float* W_qk     = (const float*)d_in[5];
  const float* b_qk     = (const float*)d_in[6];
  const float* os_gamma = (const float*)d_in[7];
  const float* os_beta  = (const float*)d_in[8];
  const float* W_out    = (const float*)d_in[9];
  const float* b_out    = (const float*)d_in[10];
  float* out = (float*)d_out;

  char* w = (char*)d_ws;
  auto ws = [&](size_t bytes) { char* p = w; w += bytes; return (unsigned short*)p; };
  unsigned short* WT     = ws(8650752);   // [4224][1024] bf16 (Wh cols | Wqk cols)
  unsigned short* WoT    = ws(4194304);   // [1024][2048]
  unsigned short* normed = ws(16777216);  // [8192][1024]
  unsigned short* vT     = ws(33554432);  // [4][2048 e][2048 n]
  unsigned short* gate   = ws(33554432);  // [8192][2048]
  unsigned short* qq     = ws(2097152);
  unsigned short* qkh    = ws(2097152);
  unsigned short* lq     = ws(2097152);
  unsigned short* lkT    = ws(2097152);   // [4][128][2048]
  unsigned short* attn   = ws(4194304);   // [32][256][256]
  unsigned short* lkvP   = ws(16777216);  // [32 slabs][2048][128] bf16 partials
  unsigned short* lkvT   = ws(2097152);   // [4][2048 e][128 d] bf16
  unsigned short* A3     = ws(33554432);  // [8192][2048]
  unsigned int*   flag   = (unsigned int*)ws(256);

  static bool s_attr = false;
  if (!s_attr) {
    hipFuncSetAttribute((const void*)gemm8p,
                        hipFuncAttributeMaxDynamicSharedMemorySize, 131072);
    hipFuncSetAttribute((const void*)gemmQL,
                        hipFuncAttributeMaxDynamicSharedMemorySize, 131072);
    hipFuncSetAttribute((const void*)gemmWo,
                        hipFuncAttributeMaxDynamicSharedMemorySize, 98304);
    s_attr = true;
  }

  {  // weight transposes + layernorm + flag-zero in one dispatch
    PrepP p{W_hidden, W_out, W_qk, x, ln_g, ln_b, WT, WoT, normed, flag};
    prep_kernel<<<14465, 256, 0, stream>>>(p);
  }
  {  // GEMM1: qk (0..31, release flag) + v/gate (32..543) + fused ARELU (544..671)
    G8P p{normed, WT, b_hidden, b_qk, os_gamma, os_beta,
          vT, gate, qq, lq, qkh, lkT, attn, flag};
    gemm8p<<<dim3(672, 1, 1), 512, 131072, stream>>>(p);
  }
  {  // lin_kv partials: slab[z=b*8+s][e][d] = vT[b][e][sK] @ lkT[b][d][sK] / 2048
    GemmP p{}; p.A = vT; p.B = lkT; p.K = 256; p.lda = 2048; p.ldb = 2048;
    p.ldc = 128; p.aZ = 4194304; p.bZ = 262144;
    p.scale = 1.f / 2048.f; p.outU = lkvP;
    gemm_part<<<dim3(16, 1, 32), 256, 0, stream>>>(p);
  }
  reduce_cvt<<<1024, 256, 0, stream>>>(lkvP, lkvT);
  {  // A3 = gate * (attn @ vg + lin_q @ lin_kv)   (8-wave, 12-tile unified ring)
    GQLP p{attn, vT, lq, lkvT, gate, A3};
    gemmQL<<<dim3(256, 1, 1), 512, 131072, stream>>>(p);
  }
  {  // out = A3 @ W_out + b_out + x  (8-wave pipelined, 256 blocks = 1/CU)
    GWoP p{A3, WoT, b_out, x, out};
    gemmWo<<<dim3(256, 1, 1), 512, 98304, stream>>>(p);
  }
}

// Round 6
// 314.689 us; speedup vs baseline: 1.1257x; 1.1257x over previous
//
#include <hip/hip_runtime.h>
#include <stdint.h>

typedef __attribute__((ext_vector_type(8))) short bf16x8_t;   // 8 bf16 in 4 VGPRs
typedef __attribute__((ext_vector_type(4))) float f32x4_t;

#define DI __device__ __forceinline__
#define SBAR() asm volatile("s_barrier" ::: "memory")
#define VMW(n) asm volatile("s_waitcnt vmcnt(" #n ")" ::: "memory")

DI unsigned short f2b(float f) {
  union { float f; unsigned int u; } c; c.f = f;
  unsigned int u = c.u + 0x7FFFu + ((c.u >> 16) & 1u);   // RNE
  return (unsigned short)(u >> 16);
}
DI unsigned int pack2(float lo, float hi) {
  return (unsigned int)f2b(lo) | ((unsigned int)f2b(hi) << 16);
}
DI float b2f(unsigned short h) {
  union { unsigned int u; float f; } c; c.u = ((unsigned int)h) << 16;
  return c.f;
}
DI float silu_f(float z) { return z / (1.0f + __expf(-z)); }

// async global->LDS, 16B per lane; LDS dst = wave-uniform base + lane*16B
DI void load_lds16(const unsigned short* g, unsigned short* l) {
  __builtin_amdgcn_global_load_lds(
      (const __attribute__((address_space(1))) unsigned int*)g,
      (__attribute__((address_space(3))) unsigned int*)l,
      16, 0, 0);
}

// ---------------------------------------------------------------- prep mega-kernel
struct PrepP {
  const float *Wh, *Wo, *Wqk, *x, *g, *b;
  unsigned short *WT, *WoT, *normed;
};

__global__ __launch_bounds__(256) void prep_kernel(PrepP p) {
  const int blk = blockIdx.x;
  const int tx = threadIdx.x & 31, ty = threadIdx.x >> 5;
  if (blk < 6272) {
    const float* in; unsigned short* out; int R, C, gx;
    if (blk < 4096)      { in = p.Wh;  out = p.WT;                 R = 1024; C = 4096; gx = blk; }
    else if (blk < 6144) { in = p.Wo;  out = p.WoT;                R = 2048; C = 1024; gx = blk - 4096; }
    else                 { in = p.Wqk; out = p.WT + 4096 * 1024;   R = 1024; C = 128;  gx = blk - 6144; }
    const int xTiles = C >> 5;
    const int c0 = (gx % xTiles) * 32, r0 = (gx / xTiles) * 32;
    __shared__ float tile[32][33];
#pragma unroll
    for (int i = 0; i < 4; ++i)
      tile[ty + 8 * i][tx] = in[(long)(r0 + ty + 8 * i) * C + c0 + tx];
    __syncthreads();
#pragma unroll
    for (int i = 0; i < 4; ++i)
      out[(long)(c0 + ty + 8 * i) * R + r0 + tx] = f2b(tile[tx][ty + 8 * i]);
  } else {
    const int row = blk - 6272, tid = threadIdx.x;
    __shared__ float red[8];
    float4 v = ((const float4*)(p.x + (long)row * 1024))[tid];
    float s = v.x + v.y + v.z + v.w;
    float ss = v.x * v.x + v.y * v.y + v.z * v.z + v.w * v.w;
    for (int o = 32; o > 0; o >>= 1) { s += __shfl_down(s, o); ss += __shfl_down(ss, o); }
    const int wave = tid >> 6, lane = tid & 63;
    if (lane == 0) { red[wave * 2] = s; red[wave * 2 + 1] = ss; }
    __syncthreads();
    if (tid == 0) {
      float S = red[0] + red[2] + red[4] + red[6];
      float SS = red[1] + red[3] + red[5] + red[7];
      float mu = S * (1.0f / 1024.0f);
      float var = SS * (1.0f / 1024.0f) - mu * mu;
      red[0] = mu; red[1] = rsqrtf(var + 1e-5f);
    }
    __syncthreads();
    const float mu = red[0], rstd = red[1];
    float4 gg = ((const float4*)p.g)[tid];
    float4 bb = ((const float4*)p.b)[tid];
    ushort4 o;
    o.x = f2b((v.x - mu) * rstd * gg.x + bb.x);
    o.y = f2b((v.y - mu) * rstd * gg.y + bb.y);
    o.z = f2b((v.z - mu) * rstd * gg.z + bb.z);
    o.w = f2b((v.w - mu) * rstd * gg.w + bb.w);
    ((ushort4*)(p.normed + (long)row * 1024))[tid] = o;
  }
}

// ---------------------------------------------------------------- reduce 8 bf16 slabs -> bf16
__global__ __launch_bounds__(256) void reduce_cvt(
    const unsigned short* __restrict__ part, unsigned short* __restrict__ out) {
  const int idx = blockIdx.x * 256 + threadIdx.x;
  const int b = idx >> 16, i = idx & 65535;
  float4 s = make_float4(0.f, 0.f, 0.f, 0.f);
#pragma unroll
  for (int sl = 0; sl < 8; ++sl) {
    ushort4 v = ((const ushort4*)part)[(long)(b * 8 + sl) * 65536 + i];
    s.x += b2f(v.x); s.y += b2f(v.y); s.z += b2f(v.z); s.w += b2f(v.w);
  }
  ushort4 o;
  o.x = f2b(s.x); o.y = f2b(s.y); o.z = f2b(s.z); o.w = f2b(s.w);
  ((ushort4*)out)[(long)b * 65536 + i] = o;
}

// ---------------------------------------------------------------- 8-wave 256^2 deep-pipelined GEMM1
// R9: reverted R8's fusion + swizzle (both regressed; FETCH rose and the whole
// loop dilated uniformly -> codegen perturbation). New: BARRIER DIET — 4->1
// s_barrier per K-tile. Hazard analysis: stages at tile t write slot t+3==t-1,
// whose reads completed before every wave's own MFMA (lgkm) and hence before
// the end-of-(t-1) barrier; frag reads of slot t race with nothing. Only the
// end-of-tile {counted VMW + SBAR} is required.
struct G8P {
  const unsigned short* A;
  const unsigned short* B;
  const float* bias;          // b_hidden[4096]
  const float* bias2;         // b_qk[128]
  const float* gamma;         // os_gamma [4][128]
  const float* beta;          // os_beta  [4][128]
  unsigned short* vTout;      // [4][2048 e][2048 n]
  unsigned short* gateOut;    // [8192][2048]
  unsigned short* qqO;        // [8192][128]
  unsigned short* lqO;
  unsigned short* qkhO;
  unsigned short* lkTO;       // [4][128][2048]
};

__global__ __launch_bounds__(512, 2) void gemm8p(G8P p) {
  extern __shared__ unsigned char lds[];   // 131072 B dynamic
  const int tid  = threadIdx.x;
  const int lane = tid & 63;
  const int wave = tid >> 6;
  const bool qk = blockIdx.x < 32;
  int bx, by;
  if (qk) { bx = blockIdx.x; by = 16; }                // B rows 4096..
  else    { const int vg = blockIdx.x - 32; bx = vg >> 4; by = vg & 15; }
  const int wm = (wave & 1) * 128;
  const int wn = (wave >> 1) * 64;
  const int lm = lane & 15;
  const int kb = lane >> 4;

  // ---- staging coords (pre-swizzled global source; LDS lands linear) ----
  const int rA  = tid >> 2;                                    // 0..127
  const int kby = ((tid & 3) << 4) ^ (((rA >> 1) & 3) << 4);   // 2-way swizzle
  const unsigned short* gA0 = p.A + (long)(bx * 256 + rA) * 1024 + (kby >> 1);
  const unsigned short* gA1 = gA0 + 128 * 1024;
  const unsigned short* gB0 = p.B + (long)(by * 256 + rA) * 1024 + (kby >> 1);
  const unsigned short* gB1 = gB0 + 128 * 1024;

  // ---- fragment-read lane constant ((row>>1)&3 == (lm>>1)&3 for all reps) ----
  const int fxor = (kb << 4) ^ (((lm >> 1) & 3) << 4);

  f32x4_t acc[8][4];
#pragma unroll
  for (int i = 0; i < 8; ++i)
#pragma unroll
    for (int j = 0; j < 4; ++j) acc[i][j] = (f32x4_t){0.f, 0.f, 0.f, 0.f};

  auto stageA = [&](int t) {
    unsigned short* l = (unsigned short*)(lds + (t & 3) * 32768 + wave * 1024);
    load_lds16(gA0 + t * 32, l);
    load_lds16(gA1 + t * 32, (unsigned short*)((unsigned char*)l + 8192));
  };
  auto stageB = [&](int t) {
    unsigned short* l = (unsigned short*)(lds + (t & 3) * 32768 + 16384 + wave * 1024);
    load_lds16(gB0 + t * 32, l);
    load_lds16(gB1 + t * 32, (unsigned short*)((unsigned char*)l + 8192));
  };

  // prologue: 3 tiles in flight (12 loads/thread)
#pragma unroll
  for (int u = 0; u < 3; ++u) { stageA(u); stageB(u); }
  VMW(8);
  SBAR();

  constexpr int NT = 16;
#pragma unroll 1
  for (int t = 0; t < NT; ++t) {
    const unsigned char* slot = lds + (t & 3) * 32768;
    bf16x8_t bF[4], aF[4];
#pragma unroll
    for (int j = 0; j < 4; ++j)
      bF[j] = *(const bf16x8_t*)(slot + 16384 + (wn + j * 16 + lm) * 64 + fxor);
#pragma unroll
    for (int i = 0; i < 4; ++i)
      aF[i] = *(const bf16x8_t*)(slot + (wm + i * 16 + lm) * 64 + fxor);
    if (t <= NT - 4) stageA(t + 3);
    __builtin_amdgcn_s_setprio(1);
#pragma unroll
    for (int i = 0; i < 4; ++i)
#pragma unroll
      for (int j = 0; j < 4; ++j)
        acc[i][j] = __builtin_amdgcn_mfma_f32_16x16x32_bf16(aF[i], bF[j], acc[i][j], 0, 0, 0);
    __builtin_amdgcn_s_setprio(0);
#pragma unroll
    for (int i = 0; i < 4; ++i)
      aF[i] = *(const bf16x8_t*)(slot + (wm + 64 + i * 16 + lm) * 64 + fxor);
    if (t <= NT - 4) stageB(t + 3);
    __builtin_amdgcn_s_setprio(1);
#pragma unroll
    for (int i = 0; i < 4; ++i)
#pragma unroll
      for (int j = 0; j < 4; ++j)
        acc[i + 4][j] = __builtin_amdgcn_mfma_f32_16x16x32_bf16(aF[i], bF[j], acc[i + 4][j], 0, 0, 0);
    __builtin_amdgcn_s_setprio(0);
    if (t <= NT - 4)      { VMW(8); }
    else if (t == NT - 3) { VMW(4); }
    else if (t == NT - 2) { VMW(0); }
    SBAR();   // single barrier per tile
  }

  // ---------------- epilogue ----------------
  if (qk) {
    // silu -> LDS [256][136] -> OffsetScale+RoPE. Waves 0..3 hold cols 0..127.
    unsigned short* q16 = (unsigned short*)lds;
    if (wave < 4) {
#pragma unroll
      for (int i = 0; i < 8; ++i) {
        const int rloc = wm + i * 16 + (lane >> 4) * 4;   // 0..255
#pragma unroll
        for (int j = 0; j < 4; ++j) {
          const int cl = wn + j * 16 + lm;                // 0..127
          const float bb = p.bias2[cl];
#pragma unroll
          for (int r = 0; r < 4; ++r)
            q16[(rloc + r) * 136 + cl] = f2b(silu_f(acc[i][j][r] + bb));
        }
      }
    }
    __syncthreads();
    const int j = tid & 63;
    const int rq = tid >> 6;                              // 0..7
    const float freq = powf(10000.0f, (float)j * (1.0f / 64.0f));
    float ga[4], gb[4], ea[4], eb[4];
#pragma unroll
    for (int h = 0; h < 4; ++h) {
      ga[h] = p.gamma[h * 128 + j];  gb[h] = p.gamma[h * 128 + 64 + j];
      ea[h] = p.beta[h * 128 + j];   eb[h] = p.beta[h * 128 + 64 + j];
    }
    unsigned short* outs[3] = {p.qqO, p.lqO, p.qkhO};
    for (int rr = 0; rr < 32; ++rr) {
      const int row = rr * 8 + rq;                        // 0..255
      const float x1 = b2f(q16[row * 136 + j]);
      const float x2 = b2f(q16[row * 136 + 64 + j]);
      const int tok = bx * 256 + row;
      const int pos = tok & 2047, bidx = tok >> 11;
      const float ang = (float)pos * freq;
      const float sn = sinf(ang), cs = cosf(ang);
#pragma unroll
      for (int h = 0; h < 3; ++h) {
        const float y1 = x1 * ga[h] + ea[h], y2 = x2 * gb[h] + eb[h];
        outs[h][(long)tok * 128 + j] = f2b(y1 * cs - y2 * sn);
        outs[h][(long)tok * 128 + 64 + j] = f2b(y2 * cs + y1 * sn);
      }
      const float y1 = x1 * ga[3] + ea[3], y2 = x2 * gb[3] + eb[3];
      p.lkTO[((long)bidx * 128 + j) * 2048 + pos] = f2b(y1 * cs - y2 * sn);
      p.lkTO[((long)bidx * 128 + 64 + j) * 2048 + pos] = f2b(y2 * cs + y1 * sn);
    }
  } else if (by < 8) {
    // v half: silu+bias, pack pairs, full 256x256 transpose via 128KB LDS,
    // coalesced 512B vT row stores. Chunk-XOR (e&7) kills transpose conflicts.
    unsigned int* Cx = (unsigned int*)lds;
#pragma unroll
    for (int i = 0; i < 8; ++i) {
      const int c0 = (wm + i * 16) / 2 + (lane >> 4) * 2;   // even uint col
#pragma unroll
      for (int j = 0; j < 4; ++j) {
        const int e = wn + j * 16 + lm;
        const float bb = p.bias[by * 256 + e];
        const float s0 = silu_f(acc[i][j][0] + bb);
        const float s1 = silu_f(acc[i][j][1] + bb);
        const float s2 = silu_f(acc[i][j][2] + bb);
        const float s3 = silu_f(acc[i][j][3] + bb);
        const int x = (e & 7) << 2;
        Cx[e * 128 + (c0 ^ x)]     = pack2(s0, s1);
        Cx[e * 128 + (c0 ^ x) + 1] = pack2(s2, s3);
      }
    }
    __syncthreads();
    const int bq = bx >> 3, nloc0 = (bx & 7) * 256, e0g = by * 256;
    unsigned short* dstBase = p.vTout + ((long)(bq * 2048 + e0g)) * 2048 + nloc0;
#pragma unroll
    for (int rep = 0; rep < 16; ++rep) {
      const int flat = rep * 512 + tid;
      const int e = flat >> 5, q = flat & 31;
      uint4 val = *(const uint4*)(Cx + e * 128 + ((q ^ (e & 7)) << 2));
      *(uint4*)(dstBase + (long)e * 2048 + q * 8) = val;
    }
  } else {
    // gate half
#pragma unroll
    for (int i = 0; i < 8; ++i) {
      const int row0 = bx * 256 + wm + i * 16 + (lane >> 4) * 4;
#pragma unroll
      for (int j = 0; j < 4; ++j) {
        const int colg = by * 256 + wn + j * 16 + lm;   // 2048..4095
        const float bb = p.bias[colg];
#pragma unroll
        for (int r = 0; r < 4; ++r)
          p.gateOut[(long)(row0 + r) * 2048 + colg - 2048] =
              f2b(silu_f(acc[i][j][r] + bb));
      }
    }
  }
}

// ---------------------------------------------------------------- QUADLIN: A3 = gate*(attn@vg + lq@lkv)
// R9: 3-slot ring (73728 B) -> 2 blocks/CU; BN=128 -> grid 512 = one clean
// pass at 2/CU with cross-block overlap (m114). 12-tile unified K (8 attn +
// 4 lq), counted VMW(3) steady / 3,0 tail. Barrier diet: 1 SBAR per tile.
struct GQLP {
  const unsigned short* attn;   // [32][256][256]
  const unsigned short* vT;     // [4][2048][2048]
  const unsigned short* lq;     // [8192][128]
  const unsigned short* lkvT;   // [4][2048][128]
  const unsigned short* gateIn; // [8192][2048]
  unsigned short* outU;         // A3 [8192][2048]
};

__global__ __launch_bounds__(512, 4) void gemmQL(GQLP p) {
  extern __shared__ unsigned char lds[];   // 3 * 24576 = 73728 B dynamic
  const int tid  = threadIdx.x;
  const int lane = tid & 63;
  const int wave = tid >> 6;
  const int z  = blockIdx.x >> 4;    // 0..31 (b*8+g)
  const int by = blockIdx.x & 15;    // 0..15 (n-tile of 2048, 128 wide)
  const int b = z >> 3, g = z & 7;
  const int wm = (wave & 1) * 128;
  const int wn = (wave >> 1) * 32;
  const int lm = lane & 15;
  const int kb = lane >> 4;

  const int rA  = tid >> 2;                                    // 0..127
  const int kby = ((tid & 3) << 4) ^ (((rA >> 1) & 3) << 4);
  const int swz = kby >> 1;                                    // shorts
  const unsigned short* a1 = p.attn + (long)z * 65536 + rA * 256 + swz;
  const unsigned short* a2 = p.lq + ((long)z * 256 + rA) * 128 + swz;
  const unsigned short* b1 = p.vT + (long)b * 4194304 + (long)(by * 128 + rA) * 2048 + g * 256 + swz;
  const unsigned short* b2 = p.lkvT + (long)b * 262144 + (by * 128 + rA) * 128 + swz;
  const int fxor = (kb << 4) ^ (((lm >> 1) & 3) << 4);

  f32x4_t acc[8][2];
#pragma unroll
  for (int i = 0; i < 8; ++i)
#pragma unroll
    for (int j = 0; j < 2; ++j) acc[i][j] = (f32x4_t){0.f, 0.f, 0.f, 0.f};

  auto stageA = [&](int tt) {
    unsigned char* base = lds + (tt % 3) * 24576;
    unsigned short* l  = (unsigned short*)(base + wave * 1024);
    unsigned short* lh = (unsigned short*)(base + wave * 1024 + 8192);
    if (tt < 8) { load_lds16(a1 + tt * 32, l); load_lds16(a1 + 128 * 256 + tt * 32, lh); }
    else { const int k2 = (tt - 8) * 32;
           load_lds16(a2 + k2, l); load_lds16(a2 + 128 * 128 + k2, lh); }
  };
  auto stageB = [&](int tt) {   // 128 rows x 64B = 8KB = 1 load/thread
    unsigned short* l = (unsigned short*)(lds + (tt % 3) * 24576 + 16384 + wave * 1024);
    if (tt < 8) load_lds16(b1 + tt * 32, l);
    else        load_lds16(b2 + (tt - 8) * 32, l);
  };

#pragma unroll
  for (int u = 0; u < 2; ++u) { stageA(u); stageB(u); }   // 6 in flight
  VMW(3);
  SBAR();

  constexpr int NT = 12;   // 8 (K=256 phase1) + 4 (K=128 phase2)
#pragma unroll 1
  for (int t = 0; t < NT; ++t) {
    const unsigned char* slot = lds + (t % 3) * 24576;
    bf16x8_t bF[2], aF[4];
#pragma unroll
    for (int j = 0; j < 2; ++j)
      bF[j] = *(const bf16x8_t*)(slot + 16384 + (wn + j * 16 + lm) * 64 + fxor);
#pragma unroll
    for (int i = 0; i < 4; ++i)
      aF[i] = *(const bf16x8_t*)(slot + (wm + i * 16 + lm) * 64 + fxor);
    if (t <= NT - 3) stageA(t + 2);
    __builtin_amdgcn_s_setprio(1);
#pragma unroll
    for (int i = 0; i < 4; ++i)
#pragma unroll
      for (int j = 0; j < 2; ++j)
        acc[i][j] = __builtin_amdgcn_mfma_f32_16x16x32_bf16(aF[i], bF[j], acc[i][j], 0, 0, 0);
    __builtin_amdgcn_s_setprio(0);
#pragma unroll
    for (int i = 0; i < 4; ++i)
      aF[i] = *(const bf16x8_t*)(slot + (wm + 64 + i * 16 + lm) * 64 + fxor);
    if (t <= NT - 3) stageB(t + 2);
    __builtin_amdgcn_s_setprio(1);
#pragma unroll
    for (int i = 0; i < 4; ++i)
#pragma unroll
      for (int j = 0; j < 2; ++j)
        acc[i + 4][j] = __builtin_amdgcn_mfma_f32_16x16x32_bf16(aF[i], bF[j], acc[i + 4][j], 0, 0, 0);
    __builtin_amdgcn_s_setprio(0);
    if (t <= NT - 3)      { VMW(3); }
    else if (t == NT - 2) { VMW(0); }
    SBAR();
  }

  // epilogue: A3 = gate * acc
#pragma unroll
  for (int i = 0; i < 8; ++i) {
    const int row0 = z * 256 + wm + i * 16 + (lane >> 4) * 4;
#pragma unroll
    for (int j = 0; j < 2; ++j) {
      const int col = by * 128 + wn + j * 16 + lm;
#pragma unroll
      for (int r = 0; r < 4; ++r) {
        const long idx = (long)(row0 + r) * 2048 + col;
        p.outU[idx] = f2b(b2f(p.gateIn[idx]) * acc[i][j][r]);
      }
    }
  }
}

// ---------------------------------------------------------------- FINAL: A3 @ WoT + b_out + x
// R9: barrier diet (1 SBAR/tile); otherwise R7's proven 4-slot counted-vmcnt.
struct GWoP {
  const unsigned short* A;   // A3 [8192][2048]
  const unsigned short* B;   // WoT [1024][2048]
  const float* bias;         // b_out[1024]
  const float* xres;         // x fp32 [8192][1024]
  float* outF;               // [8192][1024]
};

__global__ __launch_bounds__(512, 2) void gemmWo(GWoP p) {
  extern __shared__ unsigned char lds[];   // 4 * 24576 = 98304 B dynamic
  const int tid  = threadIdx.x;
  const int lane = tid & 63;
  const int wave = tid >> 6;
  const int bx = blockIdx.x >> 3;          // 0..31 (m-tile, 256 rows)
  const int by = blockIdx.x & 7;           // 0..7  (n-tile, 128 cols)
  const int wm = (wave & 1) * 128;
  const int wn = (wave >> 1) * 32;         // 4 n-groups of 32
  const int lm = lane & 15;
  const int kb = lane >> 4;

  const int rA  = tid >> 2;                                    // 0..127
  const int kby = ((tid & 3) << 4) ^ (((rA >> 1) & 3) << 4);
  const unsigned short* gA0 = p.A + (long)(bx * 256 + rA) * 2048 + (kby >> 1);
  const unsigned short* gA1 = gA0 + 128 * 2048;
  const unsigned short* gB0 = p.B + (long)(by * 128 + rA) * 2048 + (kby >> 1);
  const int fxor = (kb << 4) ^ (((lm >> 1) & 3) << 4);

  f32x4_t acc[8][2];
#pragma unroll
  for (int i = 0; i < 8; ++i)
#pragma unroll
    for (int j = 0; j < 2; ++j) acc[i][j] = (f32x4_t){0.f, 0.f, 0.f, 0.f};

  auto stageA = [&](int t) {
    unsigned short* l = (unsigned short*)(lds + (t & 3) * 24576 + wave * 1024);
    load_lds16(gA0 + t * 32, l);
    load_lds16(gA1 + t * 32, (unsigned short*)((unsigned char*)l + 8192));
  };
  auto stageB = [&](int t) {   // 128 rows x 64B = 8KB = 1 load/thread
    unsigned short* l = (unsigned short*)(lds + (t & 3) * 24576 + 16384 + wave * 1024);
    load_lds16(gB0 + t * 32, l);
  };

#pragma unroll
  for (int u = 0; u < 3; ++u) { stageA(u); stageB(u); }   // 9 in flight
  VMW(6);
  SBAR();

  constexpr int NT = 64;   // K=2048 / BK=32
#pragma unroll 1
  for (int t = 0; t < NT; ++t) {
    const unsigned char* slot = lds + (t & 3) * 24576;
    bf16x8_t bF[2], aF[4];
#pragma unroll
    for (int j = 0; j < 2; ++j)
      bF[j] = *(const bf16x8_t*)(slot + 16384 + (wn + j * 16 + lm) * 64 + fxor);
#pragma unroll
    for (int i = 0; i < 4; ++i)
      aF[i] = *(const bf16x8_t*)(slot + (wm + i * 16 + lm) * 64 + fxor);
    if (t <= NT - 4) stageA(t + 3);
    __builtin_amdgcn_s_setprio(1);
#pragma unroll
    for (int i = 0; i < 4; ++i)
#pragma unroll
      for (int j = 0; j < 2; ++j)
        acc[i][j] = __builtin_amdgcn_mfma_f32_16x16x32_bf16(aF[i], bF[j], acc[i][j], 0, 0, 0);
    __builtin_amdgcn_s_setprio(0);
#pragma unroll
    for (int i = 0; i < 4; ++i)
      aF[i] = *(const bf16x8_t*)(slot + (wm + 64 + i * 16 + lm) * 64 + fxor);
    if (t <= NT - 4) stageB(t + 3);
    __builtin_amdgcn_s_setprio(1);
#pragma unroll
    for (int i = 0; i < 4; ++i)
#pragma unroll
      for (int j = 0; j < 2; ++j)
        acc[i + 4][j] = __builtin_amdgcn_mfma_f32_16x16x32_bf16(aF[i], bF[j], acc[i + 4][j], 0, 0, 0);
    __builtin_amdgcn_s_setprio(0);
    if (t <= NT - 4)      { VMW(6); }
    else if (t == NT - 3) { VMW(3); }
    else if (t == NT - 2) { VMW(0); }
    SBAR();
  }

  // epilogue: + bias + x residual, fp32 out
#pragma unroll
  for (int i = 0; i < 8; ++i) {
    const int row0 = bx * 256 + wm + i * 16 + (lane >> 4) * 4;
#pragma unroll
    for (int j = 0; j < 2; ++j) {
      const int col = by * 128 + wn + j * 16 + lm;
      const float bb = p.bias[col];
#pragma unroll
      for (int r = 0; r < 4; ++r) {
        const long idx = (long)(row0 + r) * 1024 + col;
        p.outF[idx] = acc[i][j][r] + bb + p.xres[idx];
      }
    }
  }
}

// ---------------------------------------------------------------- GEMM (BT) 128^2 (ARELU/PART)
enum { EPI_ARELU, EPI_PART };

struct GemmP {
  const unsigned short* A;
  const unsigned short* B;
  int K, lda, ldb, ldc, mPerZ;
  long aZ, bZ;
  float scale;
  unsigned short* outU;
};

template <int EPI>
__global__ __launch_bounds__(256, 2) void gemm_bt(GemmP p) {
  __shared__ __align__(16) unsigned char smem[16384];
  unsigned short* As = (unsigned short*)smem;             // [128][32] bf16
  unsigned short* Bs = (unsigned short*)(smem + 8192);    // [128][32] bf16

  const int tid = threadIdx.x;
  const int lane = tid & 63;
  const int wave = tid >> 6;
  const int bx = blockIdx.x;
  const int by = blockIdx.y;
  const int z = blockIdx.z;

  unsigned short* lA = As + wave * 32 * 32;
  unsigned short* lB = Bs + wave * 32 * 32;
  const int wm = (wave & 1) * 64;
  const int wn = (wave >> 1) * 64;
  const int lm = lane & 15;
  const int kb = lane >> 4;
  const int rowSel = (wave * 32 + (lane >> 2));   // staging row within 128-tile
  const int colSel = (lane & 3) * 8;              // staging k-offset

  f32x4_t acc[4][4];
#pragma unroll
  for (int i = 0; i < 4; ++i)
#pragma unroll
    for (int j = 0; j < 4; ++j) acc[i][j] = (f32x4_t){0.f, 0.f, 0.f, 0.f};

  const unsigned short* Ag;
  const unsigned short* Bg;
  if constexpr (EPI == EPI_PART) {
    const int b = z >> 3, s = z & 7;   // split-K: 8 slices of 256
    Ag = p.A + (long)b * p.aZ + s * 256 + (long)(bx * 128 + rowSel) * p.lda + colSel;
    Bg = p.B + (long)b * p.bZ + s * 256 + (long)(by * 128 + rowSel) * p.ldb + colSel;
  } else {
    Ag = p.A + (long)z * p.aZ + (long)(bx * 128 + rowSel) * p.lda + colSel;
    Bg = p.B + (long)z * p.bZ + (long)(by * 128 + rowSel) * p.ldb + colSel;
  }
  const int a16 = 16 * p.lda, b16 = 16 * p.ldb;
  for (int kt = 0; kt < (p.K >> 5); ++kt) {
    load_lds16(Ag, lA);
    load_lds16(Ag + a16, lA + 512);
    load_lds16(Bg, lB);
    load_lds16(Bg + b16, lB + 512);
    Ag += 32; Bg += 32;
    __syncthreads();
    bf16x8_t aF[4], bF[4];
#pragma unroll
    for (int i = 0; i < 4; ++i)
      aF[i] = *(const bf16x8_t*)(As + (wm + i * 16 + lm) * 32 + kb * 8);
#pragma unroll
    for (int j = 0; j < 4; ++j)
      bF[j] = *(const bf16x8_t*)(Bs + (wn + j * 16 + lm) * 32 + kb * 8);
#pragma unroll
    for (int i = 0; i < 4; ++i)
#pragma unroll
      for (int j = 0; j < 4; ++j)
        acc[i][j] = __builtin_amdgcn_mfma_f32_16x16x32_bf16(aF[i], bF[j], acc[i][j], 0, 0, 0);
    __syncthreads();
  }

#pragma unroll
  for (int i = 0; i < 4; ++i) {
    const int row0 = bx * 128 + wm + i * 16 + (lane >> 4) * 4;
    long rowg0;
    if constexpr (EPI == EPI_PART) rowg0 = row0;           // within-slab row
    else rowg0 = (long)z * p.mPerZ + row0;
#pragma unroll
    for (int j = 0; j < 4; ++j) {
      const int col = by * 128 + wn + j * 16 + lm;
      if constexpr (EPI == EPI_ARELU) {
#pragma unroll
        for (int r = 0; r < 4; ++r) {
          float s = acc[i][j][r] * p.scale;
          s = s > 0.f ? s : 0.f;
          p.outU[(rowg0 + r) * (long)p.ldc + col] = f2b(s * s);
        }
      } else {
        unsigned short* slab = p.outU + (long)z * 262144;  // z = b*8+s
#pragma unroll
        for (int r = 0; r < 4; ++r)
          slab[(rowg0 + r) * (long)p.ldc + col] = f2b(acc[i][j][r] * p.scale);
      }
    }
  }
}

// ---------------------------------------------------------------- launch
extern "C" void kernel_launch(void* const* d_in, const int* in_sizes, int n_in,
                              void* d_out, int out_size, void* d_ws, size_t ws_size,
                              hipStream_t stream) {
  const float* x        = (const float*)d_in[0];
  const float* ln_g     = (const float*)d_in[1];
  const float* ln_b     = (const float*)d_in[2];
  const float* W_hidden = (const float*)d_in[3];
  const float* b_hidden = (const float*)d_in[4];
  const float* W_qk     = (const float*)d_in[5];
  const float* b_qk     = (const float*)d_in[6];
  const float* os_gamma = (const float*)d_in[7];
  const float* os_beta  = (const float*)d_in[8];
  const float* W_out    = (const float*)d_in[9];
  const float* b_out    = (const float*)d_in[10];
  float* out = (float*)d_out;

  char* w = (char*)d_ws;
  auto ws = [&](size_t bytes) { char* p = w; w += bytes; return (unsigned short*)p; };
  unsigned short* WT     = ws(8650752);   // [4224][1024] bf16 (Wh cols | Wqk cols)
  unsigned short* WoT    = ws(4194304);   // [1024][2048]
  unsigned short* normed = ws(16777216);  // [8192][1024]
  unsigned short* vT     = ws(33554432);  // [4][2048 e][2048 n]
  unsigned short* gate   = ws(33554432);  // [8192][2048]
  unsigned short* qq     = ws(2097152);
  unsigned short* qkh    = ws(2097152);
  unsigned short* lq     = ws(2097152);
  unsigned short* lkT    = ws(2097152);   // [4][128][2048]
  unsigned short* attn   = ws(4194304);   // [32][256][256]
  unsigned short* lkvP   = ws(16777216);  // [32 slabs][2048][128] bf16 partials
  unsigned short* lkvT   = ws(2097152);   // [4][2048 e][128 d] bf16
  unsigned short* A3     = ws(33554432);  // [8192][2048]

  static bool s_attr = false;
  if (!s_attr) {
    hipFuncSetAttribute((const void*)gemm8p,
                        hipFuncAttributeMaxDynamicSharedMemorySize, 131072);
    hipFuncSetAttribute((const void*)gemmQL,
                        hipFuncAttributeMaxDynamicSharedMemorySize, 73728);
    hipFuncSetAttribute((const void*)gemmWo,
                        hipFuncAttributeMaxDynamicSharedMemorySize, 98304);
    s_attr = true;
  }

  {  // weight transposes + layernorm in one dispatch
    PrepP p{W_hidden, W_out, W_qk, x, ln_g, ln_b, WT, WoT, normed};
    prep_kernel<<<14464, 256, 0, stream>>>(p);
  }
  {  // GEMM1: qk (blocks 0..31, dispatched first) + v->vT | gate (32..543)
    G8P p{normed, WT, b_hidden, b_qk, os_gamma, os_beta,
          vT, gate, qq, lq, qkh, lkT};
    gemm8p<<<dim3(544, 1, 1), 512, 131072, stream>>>(p);
  }
  {  // sim -> attn = relu(sim/256)^2, per (b,g)
    GemmP p{}; p.A = qq; p.B = qkh; p.K = 128; p.lda = 128; p.ldb = 128;
    p.ldc = 256; p.mPerZ = 256; p.aZ = 32768; p.bZ = 32768;
    p.scale = 1.f / 256.f; p.outU = attn;
    gemm_bt<EPI_ARELU><<<dim3(2, 2, 32), 256, 0, stream>>>(p);
  }
  {  // lin_kv partials: slab[z=b*8+s][e][d] = vT[b][e][sK] @ lkT[b][d][sK] / 2048
    GemmP p{}; p.A = vT; p.B = lkT; p.K = 256; p.lda = 2048; p.ldb = 2048;
    p.ldc = 128; p.aZ = 4194304; p.bZ = 262144;
    p.scale = 1.f / 2048.f; p.outU = lkvP;
    gemm_bt<EPI_PART><<<dim3(16, 1, 32), 256, 0, stream>>>(p);
  }
  reduce_cvt<<<1024, 256, 0, stream>>>(lkvP, lkvT);
  {  // A3 = gate * (attn @ vg + lin_q @ lin_kv)   (3-slot ring, 2 blocks/CU)
    GQLP p{attn, vT, lq, lkvT, gate, A3};
    gemmQL<<<dim3(512, 1, 1), 512, 73728, stream>>>(p);
  }
  {  // out = A3 @ W_out + b_out + x  (8-wave pipelined, 256 blocks = 1/CU)
    GWoP p{A3, WoT, b_out, x, out};
    gemmWo<<<dim3(256, 1, 1), 512, 98304, stream>>>(p);
  }
}

// Round 7
// 297.083 us; speedup vs baseline: 1.1924x; 1.0593x over previous
//
#include <hip/hip_runtime.h>
#include <stdint.h>

typedef __attribute__((ext_vector_type(8))) short bf16x8_t;   // 8 bf16 in 4 VGPRs
typedef __attribute__((ext_vector_type(4))) float f32x4_t;

#define DI __device__ __forceinline__
#define SBAR() asm volatile("s_barrier" ::: "memory")
#define VMW(n) asm volatile("s_waitcnt vmcnt(" #n ")" ::: "memory")

DI unsigned short f2b(float f) {
  union { float f; unsigned int u; } c; c.f = f;
  unsigned int u = c.u + 0x7FFFu + ((c.u >> 16) & 1u);   // RNE
  return (unsigned short)(u >> 16);
}
DI unsigned int pack2(float lo, float hi) {
  return (unsigned int)f2b(lo) | ((unsigned int)f2b(hi) << 16);
}
DI float b2f(unsigned short h) {
  union { unsigned int u; float f; } c; c.u = ((unsigned int)h) << 16;
  return c.f;
}
DI float silu_f(float z) { return z / (1.0f + __expf(-z)); }

// async global->LDS, 16B per lane; LDS dst = wave-uniform base + lane*16B
DI void load_lds16(const unsigned short* g, unsigned short* l) {
  __builtin_amdgcn_global_load_lds(
      (const __attribute__((address_space(1))) unsigned int*)g,
      (__attribute__((address_space(3))) unsigned int*)l,
      16, 0, 0);
}

// ---------------------------------------------------------------- prep mega-kernel
struct PrepP {
  const float *Wh, *Wo, *Wqk, *x, *g, *b;
  unsigned short *WT, *WoT, *normed;
};

__global__ __launch_bounds__(256) void prep_kernel(PrepP p) {
  const int blk = blockIdx.x;
  const int tx = threadIdx.x & 31, ty = threadIdx.x >> 5;
  if (blk < 6272) {
    const float* in; unsigned short* out; int R, C, gx;
    if (blk < 4096)      { in = p.Wh;  out = p.WT;                 R = 1024; C = 4096; gx = blk; }
    else if (blk < 6144) { in = p.Wo;  out = p.WoT;                R = 2048; C = 1024; gx = blk - 4096; }
    else                 { in = p.Wqk; out = p.WT + 4096 * 1024;   R = 1024; C = 128;  gx = blk - 6144; }
    const int xTiles = C >> 5;
    const int c0 = (gx % xTiles) * 32, r0 = (gx / xTiles) * 32;
    __shared__ float tile[32][33];
#pragma unroll
    for (int i = 0; i < 4; ++i)
      tile[ty + 8 * i][tx] = in[(long)(r0 + ty + 8 * i) * C + c0 + tx];
    __syncthreads();
#pragma unroll
    for (int i = 0; i < 4; ++i)
      out[(long)(c0 + ty + 8 * i) * R + r0 + tx] = f2b(tile[tx][ty + 8 * i]);
  } else {
    const int row = blk - 6272, tid = threadIdx.x;
    __shared__ float red[8];
    float4 v = ((const float4*)(p.x + (long)row * 1024))[tid];
    float s = v.x + v.y + v.z + v.w;
    float ss = v.x * v.x + v.y * v.y + v.z * v.z + v.w * v.w;
    for (int o = 32; o > 0; o >>= 1) { s += __shfl_down(s, o); ss += __shfl_down(ss, o); }
    const int wave = tid >> 6, lane = tid & 63;
    if (lane == 0) { red[wave * 2] = s; red[wave * 2 + 1] = ss; }
    __syncthreads();
    if (tid == 0) {
      float S = red[0] + red[2] + red[4] + red[6];
      float SS = red[1] + red[3] + red[5] + red[7];
      float mu = S * (1.0f / 1024.0f);
      float var = SS * (1.0f / 1024.0f) - mu * mu;
      red[0] = mu; red[1] = rsqrtf(var + 1e-5f);
    }
    __syncthreads();
    const float mu = red[0], rstd = red[1];
    float4 gg = ((const float4*)p.g)[tid];
    float4 bb = ((const float4*)p.b)[tid];
    ushort4 o;
    o.x = f2b((v.x - mu) * rstd * gg.x + bb.x);
    o.y = f2b((v.y - mu) * rstd * gg.y + bb.y);
    o.z = f2b((v.z - mu) * rstd * gg.z + bb.z);
    o.w = f2b((v.w - mu) * rstd * gg.w + bb.w);
    ((ushort4*)(p.normed + (long)row * 1024))[tid] = o;
  }
}

// ---------------------------------------------------------------- reduce 8 bf16 slabs -> bf16
__global__ __launch_bounds__(256) void reduce_cvt(
    const unsigned short* __restrict__ part, unsigned short* __restrict__ out) {
  const int idx = blockIdx.x * 256 + threadIdx.x;
  const int b = idx >> 16, i = idx & 65535;
  float4 s = make_float4(0.f, 0.f, 0.f, 0.f);
#pragma unroll
  for (int sl = 0; sl < 8; ++sl) {
    ushort4 v = ((const ushort4*)part)[(long)(b * 8 + sl) * 65536 + i];
    s.x += b2f(v.x); s.y += b2f(v.y); s.z += b2f(v.z); s.w += b2f(v.w);
  }
  ushort4 o;
  o.x = f2b(s.x); o.y = f2b(s.y); o.z = f2b(s.z); o.w = f2b(s.w);
  ((ushort4*)out)[(long)b * 65536 + i] = o;
}

// ---------------------------------------------------------------- 8-wave 256x128 deep-pipelined GEMM1
// R10: ported to gemmQL's proven 3-slot/2-blocks-per-CU geometry. BM=256,
// BN=128, 3-slot ring (73728 B) -> 2 blocks/CU (was 128KB -> 1/CU with a
// 0.875-pass idle tail). Grid 1056 = 32 qk (B rows 4096..4223 = Wqk, exactly
// one 128-wide tile) + 1024 v/gate. Counted VMW(3)/0, 1 SBAR/tile (R9 diet).
// acc[8][2]; 3 loads/thread/tile (A=2, B=1).
struct G8P {
  const unsigned short* A;
  const unsigned short* B;
  const float* bias;          // b_hidden[4096]
  const float* bias2;         // b_qk[128]
  const float* gamma;         // os_gamma [4][128]
  const float* beta;          // os_beta  [4][128]
  unsigned short* vTout;      // [4][2048 e][2048 n]
  unsigned short* gateOut;    // [8192][2048]
  unsigned short* qqO;        // [8192][128]
  unsigned short* lqO;
  unsigned short* qkhO;
  unsigned short* lkTO;       // [4][128][2048]
};

__global__ __launch_bounds__(512, 4) void gemm8p(G8P p) {
  extern __shared__ unsigned char lds[];   // 3 * 24576 = 73728 B dynamic
  const int tid  = threadIdx.x;
  const int lane = tid & 63;
  const int wave = tid >> 6;
  const bool qk = blockIdx.x < 32;
  int bx, by;
  if (qk) { bx = blockIdx.x; by = 32; }                 // B rows 4096..4223
  else    { const int vg = blockIdx.x - 32; bx = vg >> 5; by = vg & 31; }
  const int wm = (wave & 1) * 128;
  const int wn = (wave >> 1) * 32;
  const int lm = lane & 15;
  const int kb = lane >> 4;

  // ---- staging coords (pre-swizzled global source; LDS lands linear) ----
  const int rA  = tid >> 2;                                    // 0..127
  const int kby = ((tid & 3) << 4) ^ (((rA >> 1) & 3) << 4);   // 2-way swizzle
  const unsigned short* gA0 = p.A + (long)(bx * 256 + rA) * 1024 + (kby >> 1);
  const unsigned short* gA1 = gA0 + 128 * 1024;
  const int brow = qk ? 4096 : by * 128;
  const unsigned short* gB0 = p.B + (long)(brow + rA) * 1024 + (kby >> 1);

  // ---- fragment-read lane constant ((row>>1)&3 == (lm>>1)&3 for all reps) ----
  const int fxor = (kb << 4) ^ (((lm >> 1) & 3) << 4);

  f32x4_t acc[8][2];
#pragma unroll
  for (int i = 0; i < 8; ++i)
#pragma unroll
    for (int j = 0; j < 2; ++j) acc[i][j] = (f32x4_t){0.f, 0.f, 0.f, 0.f};

  auto stageA = [&](int t) {
    unsigned short* l = (unsigned short*)(lds + (t % 3) * 24576 + wave * 1024);
    load_lds16(gA0 + t * 32, l);
    load_lds16(gA1 + t * 32, (unsigned short*)((unsigned char*)l + 8192));
  };
  auto stageB = [&](int t) {   // 128 rows x 64B = 8KB = 1 load/thread
    unsigned short* l = (unsigned short*)(lds + (t % 3) * 24576 + 16384 + wave * 1024);
    load_lds16(gB0 + t * 32, l);
  };

  // prologue: 2 tiles in flight (6 loads/thread)
#pragma unroll
  for (int u = 0; u < 2; ++u) { stageA(u); stageB(u); }
  VMW(3);
  SBAR();

  constexpr int NT = 16;   // K=1024 / BK=32
#pragma unroll 1
  for (int t = 0; t < NT; ++t) {
    const unsigned char* slot = lds + (t % 3) * 24576;
    bf16x8_t bF[2], aF[4];
#pragma unroll
    for (int j = 0; j < 2; ++j)
      bF[j] = *(const bf16x8_t*)(slot + 16384 + (wn + j * 16 + lm) * 64 + fxor);
#pragma unroll
    for (int i = 0; i < 4; ++i)
      aF[i] = *(const bf16x8_t*)(slot + (wm + i * 16 + lm) * 64 + fxor);
    if (t <= NT - 3) stageA(t + 2);
    __builtin_amdgcn_s_setprio(1);
#pragma unroll
    for (int i = 0; i < 4; ++i)
#pragma unroll
      for (int j = 0; j < 2; ++j)
        acc[i][j] = __builtin_amdgcn_mfma_f32_16x16x32_bf16(aF[i], bF[j], acc[i][j], 0, 0, 0);
    __builtin_amdgcn_s_setprio(0);
#pragma unroll
    for (int i = 0; i < 4; ++i)
      aF[i] = *(const bf16x8_t*)(slot + (wm + 64 + i * 16 + lm) * 64 + fxor);
    if (t <= NT - 3) stageB(t + 2);
    __builtin_amdgcn_s_setprio(1);
#pragma unroll
    for (int i = 0; i < 4; ++i)
#pragma unroll
      for (int j = 0; j < 2; ++j)
        acc[i + 4][j] = __builtin_amdgcn_mfma_f32_16x16x32_bf16(aF[i], bF[j], acc[i + 4][j], 0, 0, 0);
    __builtin_amdgcn_s_setprio(0);
    if (t <= NT - 3)      { VMW(3); }
    else if (t == NT - 2) { VMW(0); }
    SBAR();   // single barrier per tile
  }

  // ---------------- epilogue ----------------
  if (qk) {
    // silu -> LDS [256][136] -> OffsetScale+RoPE. All 8 waves write (BN=128).
    unsigned short* q16 = (unsigned short*)lds;   // 69632 B <= 73728
#pragma unroll
    for (int i = 0; i < 8; ++i) {
      const int rloc = wm + i * 16 + (lane >> 4) * 4;   // 0..255
#pragma unroll
      for (int j = 0; j < 2; ++j) {
        const int cl = wn + j * 16 + lm;                // 0..127
        const float bb = p.bias2[cl];
#pragma unroll
        for (int r = 0; r < 4; ++r)
          q16[(rloc + r) * 136 + cl] = f2b(silu_f(acc[i][j][r] + bb));
      }
    }
    __syncthreads();
    const int j = tid & 63;
    const int rq = tid >> 6;                              // 0..7
    const float freq = powf(10000.0f, (float)j * (1.0f / 64.0f));
    float ga[4], gb[4], ea[4], eb[4];
#pragma unroll
    for (int h = 0; h < 4; ++h) {
      ga[h] = p.gamma[h * 128 + j];  gb[h] = p.gamma[h * 128 + 64 + j];
      ea[h] = p.beta[h * 128 + j];   eb[h] = p.beta[h * 128 + 64 + j];
    }
    unsigned short* outs[3] = {p.qqO, p.lqO, p.qkhO};
    for (int rr = 0; rr < 32; ++rr) {
      const int row = rr * 8 + rq;                        // 0..255
      const float x1 = b2f(q16[row * 136 + j]);
      const float x2 = b2f(q16[row * 136 + 64 + j]);
      const int tok = bx * 256 + row;
      const int pos = tok & 2047, bidx = tok >> 11;
      const float ang = (float)pos * freq;
      const float sn = sinf(ang), cs = cosf(ang);
#pragma unroll
      for (int h = 0; h < 3; ++h) {
        const float y1 = x1 * ga[h] + ea[h], y2 = x2 * gb[h] + eb[h];
        outs[h][(long)tok * 128 + j] = f2b(y1 * cs - y2 * sn);
        outs[h][(long)tok * 128 + 64 + j] = f2b(y2 * cs + y1 * sn);
      }
      const float y1 = x1 * ga[3] + ea[3], y2 = x2 * gb[3] + eb[3];
      p.lkTO[((long)bidx * 128 + j) * 2048 + pos] = f2b(y1 * cs - y2 * sn);
      p.lkTO[((long)bidx * 128 + 64 + j) * 2048 + pos] = f2b(y2 * cs + y1 * sn);
    }
  } else if (by < 16) {
    // v half: silu+bias, pack pairs, 256x128 transpose via [128][128]-uint LDS
    // (64KB), chunk-XOR (e&7) kills conflicts; coalesced 512B vT row stores.
    unsigned int* Cx = (unsigned int*)lds;
#pragma unroll
    for (int i = 0; i < 8; ++i) {
      const int c0 = (wm + i * 16) / 2 + (lane >> 4) * 2;   // even uint col 0..127
#pragma unroll
      for (int j = 0; j < 2; ++j) {
        const int e = wn + j * 16 + lm;                     // 0..127
        const float bb = p.bias[by * 128 + e];
        const float s0 = silu_f(acc[i][j][0] + bb);
        const float s1 = silu_f(acc[i][j][1] + bb);
        const float s2 = silu_f(acc[i][j][2] + bb);
        const float s3 = silu_f(acc[i][j][3] + bb);
        const int x = (e & 7) << 2;
        Cx[e * 128 + (c0 ^ x)]     = pack2(s0, s1);
        Cx[e * 128 + (c0 ^ x) + 1] = pack2(s2, s3);
      }
    }
    __syncthreads();
    const int bq = bx >> 3, nloc0 = (bx & 7) * 256, e0g = by * 128;
    unsigned short* dstBase = p.vTout + ((long)(bq * 2048 + e0g)) * 2048 + nloc0;
#pragma unroll
    for (int rep = 0; rep < 8; ++rep) {
      const int flat = rep * 512 + tid;
      const int e = flat >> 5, q = flat & 31;
      uint4 val = *(const uint4*)(Cx + e * 128 + ((q ^ (e & 7)) << 2));
      *(uint4*)(dstBase + (long)e * 2048 + q * 8) = val;
    }
  } else {
    // gate half: cols 2048 + (by-16)*128 ..
#pragma unroll
    for (int i = 0; i < 8; ++i) {
      const int row0 = bx * 256 + wm + i * 16 + (lane >> 4) * 4;
#pragma unroll
      for (int j = 0; j < 2; ++j) {
        const int colg = (by - 16) * 128 + wn + j * 16 + lm;   // 0..2047
        const float bb = p.bias[2048 + colg];
#pragma unroll
        for (int r = 0; r < 4; ++r)
          p.gateOut[(long)(row0 + r) * 2048 + colg] =
              f2b(silu_f(acc[i][j][r] + bb));
      }
    }
  }
}

// ---------------------------------------------------------------- QUADLIN: A3 = gate*(attn@vg + lq@lkv)
// R9: 3-slot ring (73728 B) -> 2 blocks/CU; BN=128 -> grid 512 = one clean
// pass at 2/CU with cross-block overlap (m114). 12-tile unified K (8 attn +
// 4 lq), counted VMW(3) steady / 3,0 tail. Barrier diet: 1 SBAR per tile.
struct GQLP {
  const unsigned short* attn;   // [32][256][256]
  const unsigned short* vT;     // [4][2048][2048]
  const unsigned short* lq;     // [8192][128]
  const unsigned short* lkvT;   // [4][2048][128]
  const unsigned short* gateIn; // [8192][2048]
  unsigned short* outU;         // A3 [8192][2048]
};

__global__ __launch_bounds__(512, 4) void gemmQL(GQLP p) {
  extern __shared__ unsigned char lds[];   // 3 * 24576 = 73728 B dynamic
  const int tid  = threadIdx.x;
  const int lane = tid & 63;
  const int wave = tid >> 6;
  const int z  = blockIdx.x >> 4;    // 0..31 (b*8+g)
  const int by = blockIdx.x & 15;    // 0..15 (n-tile of 2048, 128 wide)
  const int b = z >> 3, g = z & 7;
  const int wm = (wave & 1) * 128;
  const int wn = (wave >> 1) * 32;
  const int lm = lane & 15;
  const int kb = lane >> 4;

  const int rA  = tid >> 2;                                    // 0..127
  const int kby = ((tid & 3) << 4) ^ (((rA >> 1) & 3) << 4);
  const int swz = kby >> 1;                                    // shorts
  const unsigned short* a1 = p.attn + (long)z * 65536 + rA * 256 + swz;
  const unsigned short* a2 = p.lq + ((long)z * 256 + rA) * 128 + swz;
  const unsigned short* b1 = p.vT + (long)b * 4194304 + (long)(by * 128 + rA) * 2048 + g * 256 + swz;
  const unsigned short* b2 = p.lkvT + (long)b * 262144 + (by * 128 + rA) * 128 + swz;
  const int fxor = (kb << 4) ^ (((lm >> 1) & 3) << 4);

  f32x4_t acc[8][2];
#pragma unroll
  for (int i = 0; i < 8; ++i)
#pragma unroll
    for (int j = 0; j < 2; ++j) acc[i][j] = (f32x4_t){0.f, 0.f, 0.f, 0.f};

  auto stageA = [&](int tt) {
    unsigned char* base = lds + (tt % 3) * 24576;
    unsigned short* l  = (unsigned short*)(base + wave * 1024);
    unsigned short* lh = (unsigned short*)(base + wave * 1024 + 8192);
    if (tt < 8) { load_lds16(a1 + tt * 32, l); load_lds16(a1 + 128 * 256 + tt * 32, lh); }
    else { const int k2 = (tt - 8) * 32;
           load_lds16(a2 + k2, l); load_lds16(a2 + 128 * 128 + k2, lh); }
  };
  auto stageB = [&](int tt) {   // 128 rows x 64B = 8KB = 1 load/thread
    unsigned short* l = (unsigned short*)(lds + (tt % 3) * 24576 + 16384 + wave * 1024);
    if (tt < 8) load_lds16(b1 + tt * 32, l);
    else        load_lds16(b2 + (tt - 8) * 32, l);
  };

#pragma unroll
  for (int u = 0; u < 2; ++u) { stageA(u); stageB(u); }   // 6 in flight
  VMW(3);
  SBAR();

  constexpr int NT = 12;   // 8 (K=256 phase1) + 4 (K=128 phase2)
#pragma unroll 1
  for (int t = 0; t < NT; ++t) {
    const unsigned char* slot = lds + (t % 3) * 24576;
    bf16x8_t bF[2], aF[4];
#pragma unroll
    for (int j = 0; j < 2; ++j)
      bF[j] = *(const bf16x8_t*)(slot + 16384 + (wn + j * 16 + lm) * 64 + fxor);
#pragma unroll
    for (int i = 0; i < 4; ++i)
      aF[i] = *(const bf16x8_t*)(slot + (wm + i * 16 + lm) * 64 + fxor);
    if (t <= NT - 3) stageA(t + 2);
    __builtin_amdgcn_s_setprio(1);
#pragma unroll
    for (int i = 0; i < 4; ++i)
#pragma unroll
      for (int j = 0; j < 2; ++j)
        acc[i][j] = __builtin_amdgcn_mfma_f32_16x16x32_bf16(aF[i], bF[j], acc[i][j], 0, 0, 0);
    __builtin_amdgcn_s_setprio(0);
#pragma unroll
    for (int i = 0; i < 4; ++i)
      aF[i] = *(const bf16x8_t*)(slot + (wm + 64 + i * 16 + lm) * 64 + fxor);
    if (t <= NT - 3) stageB(t + 2);
    __builtin_amdgcn_s_setprio(1);
#pragma unroll
    for (int i = 0; i < 4; ++i)
#pragma unroll
      for (int j = 0; j < 2; ++j)
        acc[i + 4][j] = __builtin_amdgcn_mfma_f32_16x16x32_bf16(aF[i], bF[j], acc[i + 4][j], 0, 0, 0);
    __builtin_amdgcn_s_setprio(0);
    if (t <= NT - 3)      { VMW(3); }
    else if (t == NT - 2) { VMW(0); }
    SBAR();
  }

  // epilogue: A3 = gate * acc
#pragma unroll
  for (int i = 0; i < 8; ++i) {
    const int row0 = z * 256 + wm + i * 16 + (lane >> 4) * 4;
#pragma unroll
    for (int j = 0; j < 2; ++j) {
      const int col = by * 128 + wn + j * 16 + lm;
#pragma unroll
      for (int r = 0; r < 4; ++r) {
        const long idx = (long)(row0 + r) * 2048 + col;
        p.outU[idx] = f2b(b2f(p.gateIn[idx]) * acc[i][j][r]);
      }
    }
  }
}

// ---------------------------------------------------------------- FINAL: A3 @ WoT + b_out + x
// R9: barrier diet (1 SBAR/tile); otherwise R7's proven 4-slot counted-vmcnt.
struct GWoP {
  const unsigned short* A;   // A3 [8192][2048]
  const unsigned short* B;   // WoT [1024][2048]
  const float* bias;         // b_out[1024]
  const float* xres;         // x fp32 [8192][1024]
  float* outF;               // [8192][1024]
};

__global__ __launch_bounds__(512, 2) void gemmWo(GWoP p) {
  extern __shared__ unsigned char lds[];   // 4 * 24576 = 98304 B dynamic
  const int tid  = threadIdx.x;
  const int lane = tid & 63;
  const int wave = tid >> 6;
  const int bx = blockIdx.x >> 3;          // 0..31 (m-tile, 256 rows)
  const int by = blockIdx.x & 7;           // 0..7  (n-tile, 128 cols)
  const int wm = (wave & 1) * 128;
  const int wn = (wave >> 1) * 32;         // 4 n-groups of 32
  const int lm = lane & 15;
  const int kb = lane >> 4;

  const int rA  = tid >> 2;                                    // 0..127
  const int kby = ((tid & 3) << 4) ^ (((rA >> 1) & 3) << 4);
  const unsigned short* gA0 = p.A + (long)(bx * 256 + rA) * 2048 + (kby >> 1);
  const unsigned short* gA1 = gA0 + 128 * 2048;
  const unsigned short* gB0 = p.B + (long)(by * 128 + rA) * 2048 + (kby >> 1);
  const int fxor = (kb << 4) ^ (((lm >> 1) & 3) << 4);

  f32x4_t acc[8][2];
#pragma unroll
  for (int i = 0; i < 8; ++i)
#pragma unroll
    for (int j = 0; j < 2; ++j) acc[i][j] = (f32x4_t){0.f, 0.f, 0.f, 0.f};

  auto stageA = [&](int t) {
    unsigned short* l = (unsigned short*)(lds + (t & 3) * 24576 + wave * 1024);
    load_lds16(gA0 + t * 32, l);
    load_lds16(gA1 + t * 32, (unsigned short*)((unsigned char*)l + 8192));
  };
  auto stageB = [&](int t) {   // 128 rows x 64B = 8KB = 1 load/thread
    unsigned short* l = (unsigned short*)(lds + (t & 3) * 24576 + 16384 + wave * 1024);
    load_lds16(gB0 + t * 32, l);
  };

#pragma unroll
  for (int u = 0; u < 3; ++u) { stageA(u); stageB(u); }   // 9 in flight
  VMW(6);
  SBAR();

  constexpr int NT = 64;   // K=2048 / BK=32
#pragma unroll 1
  for (int t = 0; t < NT; ++t) {
    const unsigned char* slot = lds + (t & 3) * 24576;
    bf16x8_t bF[2], aF[4];
#pragma unroll
    for (int j = 0; j < 2; ++j)
      bF[j] = *(const bf16x8_t*)(slot + 16384 + (wn + j * 16 + lm) * 64 + fxor);
#pragma unroll
    for (int i = 0; i < 4; ++i)
      aF[i] = *(const bf16x8_t*)(slot + (wm + i * 16 + lm) * 64 + fxor);
    if (t <= NT - 4) stageA(t + 3);
    __builtin_amdgcn_s_setprio(1);
#pragma unroll
    for (int i = 0; i < 4; ++i)
#pragma unroll
      for (int j = 0; j < 2; ++j)
        acc[i][j] = __builtin_amdgcn_mfma_f32_16x16x32_bf16(aF[i], bF[j], acc[i][j], 0, 0, 0);
    __builtin_amdgcn_s_setprio(0);
#pragma unroll
    for (int i = 0; i < 4; ++i)
      aF[i] = *(const bf16x8_t*)(slot + (wm + 64 + i * 16 + lm) * 64 + fxor);
    if (t <= NT - 4) stageB(t + 3);
    __builtin_amdgcn_s_setprio(1);
#pragma unroll
    for (int i = 0; i < 4; ++i)
#pragma unroll
      for (int j = 0; j < 2; ++j)
        acc[i + 4][j] = __builtin_amdgcn_mfma_f32_16x16x32_bf16(aF[i], bF[j], acc[i + 4][j], 0, 0, 0);
    __builtin_amdgcn_s_setprio(0);
    if (t <= NT - 4)      { VMW(6); }
    else if (t == NT - 3) { VMW(3); }
    else if (t == NT - 2) { VMW(0); }
    SBAR();
  }

  // epilogue: + bias + x residual, fp32 out
#pragma unroll
  for (int i = 0; i < 8; ++i) {
    const int row0 = bx * 256 + wm + i * 16 + (lane >> 4) * 4;
#pragma unroll
    for (int j = 0; j < 2; ++j) {
      const int col = by * 128 + wn + j * 16 + lm;
      const float bb = p.bias[col];
#pragma unroll
      for (int r = 0; r < 4; ++r) {
        const long idx = (long)(row0 + r) * 1024 + col;
        p.outF[idx] = acc[i][j][r] + bb + p.xres[idx];
      }
    }
  }
}

// ---------------------------------------------------------------- GEMM (BT) 128^2 (ARELU/PART)
enum { EPI_ARELU, EPI_PART };

struct GemmP {
  const unsigned short* A;
  const unsigned short* B;
  int K, lda, ldb, ldc, mPerZ;
  long aZ, bZ;
  float scale;
  unsigned short* outU;
};

template <int EPI>
__global__ __launch_bounds__(256, 2) void gemm_bt(GemmP p) {
  __shared__ __align__(16) unsigned char smem[16384];
  unsigned short* As = (unsigned short*)smem;             // [128][32] bf16
  unsigned short* Bs = (unsigned short*)(smem + 8192);    // [128][32] bf16

  const int tid = threadIdx.x;
  const int lane = tid & 63;
  const int wave = tid >> 6;
  const int bx = blockIdx.x;
  const int by = blockIdx.y;
  const int z = blockIdx.z;

  unsigned short* lA = As + wave * 32 * 32;
  unsigned short* lB = Bs + wave * 32 * 32;
  const int wm = (wave & 1) * 64;
  const int wn = (wave >> 1) * 64;
  const int lm = lane & 15;
  const int kb = lane >> 4;
  const int rowSel = (wave * 32 + (lane >> 2));   // staging row within 128-tile
  const int colSel = (lane & 3) * 8;              // staging k-offset

  f32x4_t acc[4][4];
#pragma unroll
  for (int i = 0; i < 4; ++i)
#pragma unroll
    for (int j = 0; j < 4; ++j) acc[i][j] = (f32x4_t){0.f, 0.f, 0.f, 0.f};

  const unsigned short* Ag;
  const unsigned short* Bg;
  if constexpr (EPI == EPI_PART) {
    const int b = z >> 3, s = z & 7;   // split-K: 8 slices of 256
    Ag = p.A + (long)b * p.aZ + s * 256 + (long)(bx * 128 + rowSel) * p.lda + colSel;
    Bg = p.B + (long)b * p.bZ + s * 256 + (long)(by * 128 + rowSel) * p.ldb + colSel;
  } else {
    Ag = p.A + (long)z * p.aZ + (long)(bx * 128 + rowSel) * p.lda + colSel;
    Bg = p.B + (long)z * p.bZ + (long)(by * 128 + rowSel) * p.ldb + colSel;
  }
  const int a16 = 16 * p.lda, b16 = 16 * p.ldb;
  for (int kt = 0; kt < (p.K >> 5); ++kt) {
    load_lds16(Ag, lA);
    load_lds16(Ag + a16, lA + 512);
    load_lds16(Bg, lB);
    load_lds16(Bg + b16, lB + 512);
    Ag += 32; Bg += 32;
    __syncthreads();
    bf16x8_t aF[4], bF[4];
#pragma unroll
    for (int i = 0; i < 4; ++i)
      aF[i] = *(const bf16x8_t*)(As + (wm + i * 16 + lm) * 32 + kb * 8);
#pragma unroll
    for (int j = 0; j < 4; ++j)
      bF[j] = *(const bf16x8_t*)(Bs + (wn + j * 16 + lm) * 32 + kb * 8);
#pragma unroll
    for (int i = 0; i < 4; ++i)
#pragma unroll
      for (int j = 0; j < 4; ++j)
        acc[i][j] = __builtin_amdgcn_mfma_f32_16x16x32_bf16(aF[i], bF[j], acc[i][j], 0, 0, 0);
    __syncthreads();
  }

#pragma unroll
  for (int i = 0; i < 4; ++i) {
    const int row0 = bx * 128 + wm + i * 16 + (lane >> 4) * 4;
    long rowg0;
    if constexpr (EPI == EPI_PART) rowg0 = row0;           // within-slab row
    else rowg0 = (long)z * p.mPerZ + row0;
#pragma unroll
    for (int j = 0; j < 4; ++j) {
      const int col = by * 128 + wn + j * 16 + lm;
      if constexpr (EPI == EPI_ARELU) {
#pragma unroll
        for (int r = 0; r < 4; ++r) {
          float s = acc[i][j][r] * p.scale;
          s = s > 0.f ? s : 0.f;
          p.outU[(rowg0 + r) * (long)p.ldc + col] = f2b(s * s);
        }
      } else {
        unsigned short* slab = p.outU + (long)z * 262144;  // z = b*8+s
#pragma unroll
        for (int r = 0; r < 4; ++r)
          slab[(rowg0 + r) * (long)p.ldc + col] = f2b(acc[i][j][r] * p.scale);
      }
    }
  }
}

// ---------------------------------------------------------------- launch
extern "C" void kernel_launch(void* const* d_in, const int* in_sizes, int n_in,
                              void* d_out, int out_size, void* d_ws, size_t ws_size,
                              hipStream_t stream) {
  const float* x        = (const float*)d_in[0];
  const float* ln_g     = (const float*)d_in[1];
  const float* ln_b     = (const float*)d_in[2];
  const float* W_hidden = (const float*)d_in[3];
  const float* b_hidden = (const float*)d_in[4];
  const float* W_qk     = (const float*)d_in[5];
  const float* b_qk     = (const float*)d_in[6];
  const float* os_gamma = (const float*)d_in[7];
  const float* os_beta  = (const float*)d_in[8];
  const float* W_out    = (const float*)d_in[9];
  const float* b_out    = (const float*)d_in[10];
  float* out = (float*)d_out;

  char* w = (char*)d_ws;
  auto ws = [&](size_t bytes) { char* p = w; w += bytes; return (unsigned short*)p; };
  unsigned short* WT     = ws(8650752);   // [4224][1024] bf16 (Wh cols | Wqk cols)
  unsigned short* WoT    = ws(4194304);   // [1024][2048]
  unsigned short* normed = ws(16777216);  // [8192][1024]
  unsigned short* vT     = ws(33554432);  // [4][2048 e][2048 n]
  unsigned short* gate   = ws(33554432);  // [8192][2048]
  unsigned short* qq     = ws(2097152);
  unsigned short* qkh    = ws(2097152);
  unsigned short* lq     = ws(2097152);
  unsigned short* lkT    = ws(2097152);   // [4][128][2048]
  unsigned short* attn   = ws(4194304);   // [32][256][256]
  unsigned short* lkvP   = ws(16777216);  // [32 slabs][2048][128] bf16 partials
  unsigned short* lkvT   = ws(2097152);   // [4][2048 e][128 d] bf16
  unsigned short* A3     = ws(33554432);  // [8192][2048]

  static bool s_attr = false;
  if (!s_attr) {
    hipFuncSetAttribute((const void*)gemm8p,
                        hipFuncAttributeMaxDynamicSharedMemorySize, 73728);
    hipFuncSetAttribute((const void*)gemmQL,
                        hipFuncAttributeMaxDynamicSharedMemorySize, 73728);
    hipFuncSetAttribute((const void*)gemmWo,
                        hipFuncAttributeMaxDynamicSharedMemorySize, 98304);
    s_attr = true;
  }

  {  // weight transposes + layernorm in one dispatch
    PrepP p{W_hidden, W_out, W_qk, x, ln_g, ln_b, WT, WoT, normed};
    prep_kernel<<<14464, 256, 0, stream>>>(p);
  }
  {  // GEMM1: qk (blocks 0..31, dispatched first) + v->vT | gate (32..1055)
    G8P p{normed, WT, b_hidden, b_qk, os_gamma, os_beta,
          vT, gate, qq, lq, qkh, lkT};
    gemm8p<<<dim3(1056, 1, 1), 512, 73728, stream>>>(p);
  }
  {  // sim -> attn = relu(sim/256)^2, per (b,g)
    GemmP p{}; p.A = qq; p.B = qkh; p.K = 128; p.lda = 128; p.ldb = 128;
    p.ldc = 256; p.mPerZ = 256; p.aZ = 32768; p.bZ = 32768;
    p.scale = 1.f / 256.f; p.outU = attn;
    gemm_bt<EPI_ARELU><<<dim3(2, 2, 32), 256, 0, stream>>>(p);
  }
  {  // lin_kv partials: slab[z=b*8+s][e][d] = vT[b][e][sK] @ lkT[b][d][sK] / 2048
    GemmP p{}; p.A = vT; p.B = lkT; p.K = 256; p.lda = 2048; p.ldb = 2048;
    p.ldc = 128; p.aZ = 4194304; p.bZ = 262144;
    p.scale = 1.f / 2048.f; p.outU = lkvP;
    gemm_bt<EPI_PART><<<dim3(16, 1, 32), 256, 0, stream>>>(p);
  }
  reduce_cvt<<<1024, 256, 0, stream>>>(lkvP, lkvT);
  {  // A3 = gate * (attn @ vg + lin_q @ lin_kv)   (3-slot ring, 2 blocks/CU)
    GQLP p{attn, vT, lq, lkvT, gate, A3};
    gemmQL<<<dim3(512, 1, 1), 512, 73728, stream>>>(p);
  }
  {  // out = A3 @ W_out + b_out + x  (8-wave pipelined, 256 blocks = 1/CU)
    GWoP p{A3, WoT, b_out, x, out};
    gemmWo<<<dim3(256, 1, 1), 512, 98304, stream>>>(p);
  }
}